// Round 4
// baseline (1311.524 us; speedup 1.0000x reference)
//
#include <hip/hip_runtime.h>
#include <hip/hip_bf16.h>
#include <math.h>

#define Tn 1024
#define Cn 960
#define Hn 15
#define Nn 64
#define Mn 4096  // B*T

__device__ __forceinline__ float sigmf(float x) { return 1.0f / (1.0f + __expf(-x)); }

// ---------------------------------------------------------------------------
// token-shift + 6 mixes: out_j = x + (shift(x) - x) * mix_j
// ---------------------------------------------------------------------------
__global__ __launch_bounds__(256) void mix6_kernel(
    const float* __restrict__ x,
    const float* __restrict__ mr, const float* __restrict__ mw, const float* __restrict__ mk,
    const float* __restrict__ mv, const float* __restrict__ ma, const float* __restrict__ mg,
    float* __restrict__ o_r, float* __restrict__ o_w, float* __restrict__ o_k,
    float* __restrict__ o_v, float* __restrict__ o_a, float* __restrict__ o_g)
{
    int idx = blockIdx.x * 256 + threadIdx.x;  // float4 index
    int e = idx * 4;
    if (e >= Mn * Cn) return;
    int m = e / Cn;
    int c = e - m * Cn;
    int t = m & (Tn - 1);
    float4 xv = *(const float4*)(x + e);
    float4 xp = make_float4(0.f, 0.f, 0.f, 0.f);
    if (t > 0) xp = *(const float4*)(x + e - Cn);
    float4 dx = make_float4(xp.x - xv.x, xp.y - xv.y, xp.z - xv.z, xp.w - xv.w);
#define APPLY(MIXP, OUTP)                                                     \
    {                                                                         \
        float4 mm = *(const float4*)(MIXP + c);                               \
        float4 o = make_float4(xv.x + dx.x * mm.x, xv.y + dx.y * mm.y,        \
                               xv.z + dx.z * mm.z, xv.w + dx.w * mm.w);       \
        *(float4*)(OUTP + e) = o;                                             \
    }
    APPLY(mr, o_r) APPLY(mw, o_w) APPLY(mk, o_k)
    APPLY(mv, o_v) APPLY(ma, o_a) APPLY(mg, o_g)
#undef APPLY
}

// ---------------------------------------------------------------------------
// plain f32 GEMM: C[M,N] = A[M,K] @ B[K,N].  M from grid (64/row-tile).
// BM=64 BN=64 BK=16, 256 threads, 4x4 per thread.
// ---------------------------------------------------------------------------
__global__ __launch_bounds__(256) void gemm64_kernel(
    const float* __restrict__ A, int lda,
    const float* __restrict__ Bw, int ldb,
    float* __restrict__ Cc, int ldc, int N, int K)
{
    __shared__ float As[16][68];
    __shared__ float Bs[16][64];
    int bm = blockIdx.x * 64, bn = blockIdx.y * 64;
    int tid = threadIdx.x;
    int tx = tid & 15, ty = tid >> 4;
    int ar = tid >> 2, ak = (tid & 3) * 4;
    int bkr = tid >> 4, bnc = (tid & 15) * 4;
    bool bok = (bn + bnc) < N;
    const float* Aptr = A + (size_t)(bm + ar) * lda + ak;
    const float* Bptr = Bw + (size_t)bkr * ldb + bn + bnc;
    float acc[4][4];
#pragma unroll
    for (int i = 0; i < 4; ++i)
#pragma unroll
        for (int j = 0; j < 4; ++j) acc[i][j] = 0.f;

    for (int k0 = 0; k0 < K; k0 += 16) {
        float4 a4 = *(const float4*)(Aptr + k0);
        float4 b4 = make_float4(0.f, 0.f, 0.f, 0.f);
        if (bok) b4 = *(const float4*)(Bptr + (size_t)k0 * ldb);
        As[ak + 0][ar] = a4.x;
        As[ak + 1][ar] = a4.y;
        As[ak + 2][ar] = a4.z;
        As[ak + 3][ar] = a4.w;
        *(float4*)&Bs[bkr][bnc] = b4;
        __syncthreads();
#pragma unroll
        for (int kk = 0; kk < 16; ++kk) {
            float4 av = *(const float4*)&As[kk][ty * 4];
            float4 bv = *(const float4*)&Bs[kk][tx * 4];
            float aa[4] = {av.x, av.y, av.z, av.w};
            float bb[4] = {bv.x, bv.y, bv.z, bv.w};
#pragma unroll
            for (int i = 0; i < 4; ++i)
#pragma unroll
                for (int j = 0; j < 4; ++j) acc[i][j] += aa[i] * bb[j];
        }
        __syncthreads();
    }
    if (bok) {
#pragma unroll
        for (int i = 0; i < 4; ++i) {
            int row = bm + ty * 4 + i;
            float4 st = make_float4(acc[i][0], acc[i][1], acc[i][2], acc[i][3]);
            *(float4*)(Cc + (size_t)row * ldc + bn + tx * 4) = st;
        }
    }
}

// ---------------------------------------------------------------------------
// activations on hid: cols [0,64) tanh (w), [160,288) sigmoid (g)
// ---------------------------------------------------------------------------
__global__ __launch_bounds__(256) void hidact_kernel(float* hid)
{
    int idx = blockIdx.x * 256 + threadIdx.x;
    if (idx >= Mn * 288) return;
    int c = idx % 288;
    float v = hid[idx];
    if (c < 64) v = tanhf(v);
    else if (c >= 160) v = sigmf(v);
    hid[idx] = v;
}

// ---------------------------------------------------------------------------
// elementwise stage 3: w, a, v-residual, kk-norm, kh, ah, bh.
// ---------------------------------------------------------------------------
__global__ __launch_bounds__(256) void stage3e_kernel(
    const float* wrawp, const float* aprep, const float* vsigp,
    const float* kraw, const float* vfirst,
    const float* w0, const float* a0, const float* v0c,
    const float* kkc, const float* kac,
    float* w_out, float* v_io, float* ah_out, float* bh_out, float* kh_out)
{
    int p = blockIdx.x * 4 + (threadIdx.x >> 6);
    int l = threadIdx.x & 63;
    int m = p / Hn;
    int h = p - m * Hn;
    int c = h * 64 + l;
    size_t idx = (size_t)m * Cn + c;
    float k = kraw[idx];
    float wr = w0[c] + wrawp[idx];
    float a = sigmf(a0[c] + aprep[idx]);
    float vs = sigmf(v0c[c] + vsigp[idx]);
    float v0g = v_io[idx];
    float v = v0g + (vfirst[idx] - v0g) * vs;
    float kk = k * kkc[c];
    float ss = kk * kk;
#pragma unroll
    for (int o = 32; o; o >>= 1) ss += __shfl_xor(ss, o);
    float inv = 1.0f / fmaxf(sqrtf(ss), 1e-12f);
    kk *= inv;
    float w = sigmf(wr) * 0.60653065971263342f;  // sigmoid(wr)*exp(-0.5)
    float kh = k * (1.0f + (a - 1.0f) * kac[c]);
    w_out[idx] = w;
    v_io[idx] = v;
    ah_out[idx] = -kk;
    bh_out[idx] = kk * a;
    kh_out[idx] = kh;
}

// ---------------------------------------------------------------------------
// barrier-free sequential WKV scan, depth-4 ring pipeline.
// grid = B*H*4 blocks of ONE wave. Block (bh,q) owns rows [16q,16q+16).
// lane = (row=l>>2, cg=l&3) owns 16 state cols of one row. Loads for step
// t+4 issued at step t; at each ds_write the 18 newer loads stay outstanding
// (counted vmcnt) -> ~3.5 compute bodies cover the ~900cy load latency.
// Single wave per block: wave-synchronous LDS, lgkmcnt only, NO s_barrier.
// ---------------------------------------------------------------------------
__global__ __launch_bounds__(64) void scan_kernel(
    const float* __restrict__ rP, const float* __restrict__ wP,
    const float* __restrict__ kP, const float* __restrict__ aP,
    const float* __restrict__ bP, const float* __restrict__ vP,
    float* __restrict__ wkv)
{
    __shared__ float buf[4][6][64];  // [phase][r,w,k,a,b,v][64]
    int l = threadIdx.x;
    int blk = blockIdx.x;
    int bh = blk >> 2, q = blk & 3;
    int bb = bh / Hn, h = bh - bb * Hn;
    size_t base = (size_t)bb * Tn * Cn + h * 64;
    int rl = l >> 2, cg = l & 3;
    int c0 = cg * 16;
    int arow = q * 16 + rl;

    const float* pr = rP + base + l;
    const float* pw = wP + base + l;
    const float* pk = kP + base + l;
    const float* pa = aP + base + l;
    const float* pb = bP + base + l;
    const float* pv = vP + base + l;

    float s[16];
#pragma unroll
    for (int z = 0; z < 16; ++z) s[z] = 0.f;

    float* po = wkv + base + arow;

#define DECLSET(S) float S##0, S##1, S##2, S##3, S##4, S##5;
#define LOADSET(S)                                                            \
    S##0 = *pr; S##1 = *pw; S##2 = *pk; S##3 = *pa; S##4 = *pb; S##5 = *pv;
#define ADVANCE(COND)                                                         \
    {                                                                         \
        int adv = (COND) ? Cn : 0;                                            \
        pr += adv; pw += adv; pk += adv; pa += adv; pb += adv; pv += adv;     \
    }
#define WRITESET(P, S)                                                        \
    buf[P][0][l] = S##0; buf[P][1][l] = S##1; buf[P][2][l] = S##2;            \
    buf[P][3][l] = S##3; buf[P][4][l] = S##4; buf[P][5][l] = S##5;

    DECLSET(Ra) DECLSET(Rb) DECLSET(Rc) DECLSET(Rd)
    // preload steps 0..3; pointers end at step 4
    LOADSET(Ra) ADVANCE(1)
    LOADSET(Rb) ADVANCE(1)
    LOADSET(Rc) ADVANCE(1)
    LOADSET(Rd) ADVANCE(1)

#define STEPCOMPUTE(H)                                                        \
    {                                                                         \
        float sp0 = 0.f, sp1 = 0.f, sp2 = 0.f, sp3 = 0.f;                     \
        _Pragma("unroll")                                                     \
        for (int z = 0; z < 16; z += 4) {                                     \
            float4 a4 = *(const float4*)&buf[H][3][c0 + z];                   \
            sp0 += s[z + 0] * a4.x; sp1 += s[z + 1] * a4.y;                   \
            sp2 += s[z + 2] * a4.z; sp3 += s[z + 3] * a4.w;                   \
        }                                                                     \
        float sa = (sp0 + sp1) + (sp2 + sp3);                                 \
        sa += __shfl_xor(sa, 1);                                              \
        sa += __shfl_xor(sa, 2);                                              \
        float vi = buf[H][5][arow];                                           \
        float op0 = 0.f, op1 = 0.f, op2 = 0.f, op3 = 0.f;                     \
        _Pragma("unroll")                                                     \
        for (int z = 0; z < 16; z += 4) {                                     \
            float4 w4 = *(const float4*)&buf[H][1][c0 + z];                   \
            float4 k4 = *(const float4*)&buf[H][2][c0 + z];                   \
            float4 b4 = *(const float4*)&buf[H][4][c0 + z];                   \
            float4 r4 = *(const float4*)&buf[H][0][c0 + z];                   \
            s[z + 0] = s[z + 0] * w4.x + sa * b4.x + vi * k4.x; op0 += s[z + 0] * r4.x; \
            s[z + 1] = s[z + 1] * w4.y + sa * b4.y + vi * k4.y; op1 += s[z + 1] * r4.y; \
            s[z + 2] = s[z + 2] * w4.z + sa * b4.z + vi * k4.z; op2 += s[z + 2] * r4.z; \
            s[z + 3] = s[z + 3] * w4.w + sa * b4.w + vi * k4.w; op3 += s[z + 3] * r4.w; \
        }                                                                     \
        float op = (op0 + op1) + (op2 + op3);                                 \
        op += __shfl_xor(op, 1);                                              \
        op += __shfl_xor(op, 2);                                              \
        if (cg == 0) *po = op;                                                \
        po += Cn;                                                             \
    }

    // PHASE(P, S, step): ds_write step's data (waits counted-vmcnt for S's
    // loads), issue loads for step+4 into S, lgkm-wait, compute.
#define PHASE(P, S, STEP)                                                     \
    {                                                                         \
        WRITESET(P, S)                                                        \
        LOADSET(S)                                                            \
        ADVANCE((STEP) + 5 < Tn)                                              \
        asm volatile("s_waitcnt lgkmcnt(0)" ::: "memory");                    \
        STEPCOMPUTE(P)                                                        \
    }

    for (int t = 0; t < Tn; t += 4) {
        PHASE(0, Ra, t + 0)
        PHASE(1, Rb, t + 1)
        PHASE(2, Rc, t + 2)
        PHASE(3, Rd, t + 3)
    }
#undef PHASE
#undef STEPCOMPUTE
#undef WRITESET
#undef ADVANCE
#undef LOADSET
#undef DECLSET
}

// ---------------------------------------------------------------------------
// post-scan: per-head groupnorm + bonus + gate.  one wave per (m,h).
// ---------------------------------------------------------------------------
__global__ __launch_bounds__(256) void postnorm_kernel(
    const float* __restrict__ wkv, const float* __restrict__ rB,
    const float* __restrict__ kB, const float* __restrict__ vB,
    const float* __restrict__ gB, const float* __restrict__ r_k,
    const float* __restrict__ ln_g, const float* __restrict__ ln_b,
    float* __restrict__ xog)
{
    int grp = blockIdx.x * 4 + (threadIdx.x >> 6);
    int l = threadIdx.x & 63;
    int m = grp / Hn, h = grp - m * Hn;
    int c = h * 64 + l;
    size_t idx = (size_t)m * Cn + c;
    float out = wkv[idx];
    float rv = rB[idx], kv = kB[idx], vv = vB[idx];
    float m1 = out, m2 = out * out, bd = rv * kv * r_k[c];
#pragma unroll
    for (int o = 32; o; o >>= 1) {
        m1 += __shfl_xor(m1, o);
        m2 += __shfl_xor(m2, o);
        bd += __shfl_xor(bd, o);
    }
    float mean = m1 * (1.f / 64.f);
    float var = m2 * (1.f / 64.f) - mean * mean;
    float xn = (out - mean) * rsqrtf(var + 0.00064f) * ln_g[c] + ln_b[c];
    xog[idx] = (xn + bd * vv) * gB[idx];
}

// ---------------------------------------------------------------------------
extern "C" void kernel_launch(void* const* d_in, const int* in_sizes, int n_in,
                              void* d_out, int out_size, void* d_ws, size_t ws_size,
                              hipStream_t stream)
{
    const float* x       = (const float*)d_in[0];
    const float* v_first = (const float*)d_in[1];
    const float* x_r     = (const float*)d_in[2];
    const float* x_w     = (const float*)d_in[3];
    const float* x_k     = (const float*)d_in[4];
    const float* x_v     = (const float*)d_in[5];
    const float* x_a     = (const float*)d_in[6];
    const float* x_g     = (const float*)d_in[7];
    const float* w0      = (const float*)d_in[8];
    const float* w1      = (const float*)d_in[9];
    const float* w2      = (const float*)d_in[10];
    const float* a0      = (const float*)d_in[11];
    const float* a1      = (const float*)d_in[12];
    const float* a2      = (const float*)d_in[13];
    const float* v0c     = (const float*)d_in[14];
    const float* v1      = (const float*)d_in[15];
    const float* v2      = (const float*)d_in[16];
    const float* g1w     = (const float*)d_in[17];
    const float* g2w     = (const float*)d_in[18];
    const float* k_k     = (const float*)d_in[19];
    const float* k_a     = (const float*)d_in[20];
    const float* r_k     = (const float*)d_in[21];
    const float* Wr      = (const float*)d_in[22];
    const float* Wk      = (const float*)d_in[23];
    const float* Wv      = (const float*)d_in[24];
    const float* Wo      = (const float*)d_in[25];
    const float* ln_g    = (const float*)d_in[26];
    const float* ln_b    = (const float*)d_in[27];
    float* out = (float*)d_out;

    float* ws = (float*)d_ws;
    size_t MC = (size_t)Mn * Cn;
    float* B0 = ws + 0 * MC;  // xr -> wraw -> ah
    float* B1 = ws + 1 * MC;  // xw -> w    -> xog
    float* B2 = ws + 2 * MC;  // xk -> apre -> bh
    float* B3 = ws + 3 * MC;  // xv -> vsigp -> kh
    float* B4 = ws + 4 * MC;  // xa -> wkv (raw scan out)
    float* B5 = ws + 5 * MC;  // xg -> g
    float* B6 = ws + 6 * MC;  // r
    float* B7 = ws + 7 * MC;  // k (raw)
    float* B8 = ws + 8 * MC;  // v0 -> v
    float* hid = ws + 9 * MC; // [Mn,288]

    mix6_kernel<<<3840, 256, 0, stream>>>(x, x_r, x_w, x_k, x_v, x_a, x_g,
                                          B0, B1, B2, B3, B4, B5);

    dim3 gBig(64, 15);
    // stage 1: big projections
    gemm64_kernel<<<gBig, 256, 0, stream>>>(B0, Cn, Wr, Cn, B6, Cn, Cn, Cn);
    gemm64_kernel<<<gBig, 256, 0, stream>>>(B2, Cn, Wk, Cn, B7, Cn, Cn, Cn);
    gemm64_kernel<<<gBig, 256, 0, stream>>>(B3, Cn, Wv, Cn, B8, Cn, Cn, Cn);
    // stage 2: lora-down GEMMs into hid
    dim3 g64(64, 1);
    gemm64_kernel<<<g64, 256, 0, stream>>>(B1, Cn, w1, 64, hid + 0, 288, 64, Cn);
    gemm64_kernel<<<g64, 256, 0, stream>>>(B4, Cn, a1, 64, hid + 64, 288, 64, Cn);
    gemm64_kernel<<<g64, 256, 0, stream>>>(B3, Cn, v1, 32, hid + 128, 288, 32, Cn);
    gemm64_kernel<<<dim3(64, 2), 256, 0, stream>>>(B5, Cn, g1w, 128, hid + 160, 288, 128, Cn);
    hidact_kernel<<<4608, 256, 0, stream>>>(hid);
    // stage 3: lora-up GEMMs
    gemm64_kernel<<<gBig, 256, 0, stream>>>(hid + 0, 288, w2, Cn, B0, Cn, Cn, 64);
    gemm64_kernel<<<gBig, 256, 0, stream>>>(hid + 64, 288, a2, Cn, B2, Cn, Cn, 64);
    gemm64_kernel<<<gBig, 256, 0, stream>>>(hid + 128, 288, v2, Cn, B3, Cn, Cn, 32);
    gemm64_kernel<<<gBig, 256, 0, stream>>>(hid + 160, 288, g2w, Cn, B5, Cn, Cn, 128);
    // stage 3e: elementwise + head-norm
    stage3e_kernel<<<15360, 256, 0, stream>>>(B0, B2, B3, B7, v_first,
                                              w0, a0, v0c, k_k, k_a,
                                              B1, B8, B0, B2, B3);
    // stage 4: barrier-free depth-4 pipelined scan (raw wkv out)
    scan_kernel<<<240, 64, 0, stream>>>(B6, B1, B3, B0, B2, B8, B4);
    // stage 4b: groupnorm + bonus + gate
    postnorm_kernel<<<15360, 256, 0, stream>>>(B4, B6, B3, B8, B5,
                                               r_k, ln_g, ln_b, B1);
    // stage 5: output projection
    gemm64_kernel<<<gBig, 256, 0, stream>>>(B1, Cn, Wo, Cn, out, Cn, Cn, Cn);
}

// Round 5
// 1292.783 us; speedup vs baseline: 1.0145x; 1.0145x over previous
//
#include <hip/hip_runtime.h>
#include <hip/hip_bf16.h>
#include <math.h>

#define Tn 1024
#define Cn 960
#define Hn 15
#define Nn 64
#define Mn 4096  // B*T

__device__ __forceinline__ float sigmf(float x) { return 1.0f / (1.0f + __expf(-x)); }

// quad-lane (xor1 + xor2) sum via DPP quad_perm — VALU latency, no DS ops.
__device__ __forceinline__ float quadsum(float x) {
    int xi = __float_as_int(x);
    int y1 = __builtin_amdgcn_update_dpp(0, xi, 0xB1, 0xF, 0xF, true);  // [1,0,3,2]
    x += __int_as_float(y1);
    xi = __float_as_int(x);
    int y2 = __builtin_amdgcn_update_dpp(0, xi, 0x4E, 0xF, 0xF, true);  // [2,3,0,1]
    x += __int_as_float(y2);
    return x;
}

// ---------------------------------------------------------------------------
// token-shift + 6 mixes: out_j = x + (shift(x) - x) * mix_j
// ---------------------------------------------------------------------------
__global__ __launch_bounds__(256) void mix6_kernel(
    const float* __restrict__ x,
    const float* __restrict__ mr, const float* __restrict__ mw, const float* __restrict__ mk,
    const float* __restrict__ mv, const float* __restrict__ ma, const float* __restrict__ mg,
    float* __restrict__ o_r, float* __restrict__ o_w, float* __restrict__ o_k,
    float* __restrict__ o_v, float* __restrict__ o_a, float* __restrict__ o_g)
{
    int idx = blockIdx.x * 256 + threadIdx.x;  // float4 index
    int e = idx * 4;
    if (e >= Mn * Cn) return;
    int m = e / Cn;
    int c = e - m * Cn;
    int t = m & (Tn - 1);
    float4 xv = *(const float4*)(x + e);
    float4 xp = make_float4(0.f, 0.f, 0.f, 0.f);
    if (t > 0) xp = *(const float4*)(x + e - Cn);
    float4 dx = make_float4(xp.x - xv.x, xp.y - xv.y, xp.z - xv.z, xp.w - xv.w);
#define APPLY(MIXP, OUTP)                                                     \
    {                                                                         \
        float4 mm = *(const float4*)(MIXP + c);                               \
        float4 o = make_float4(xv.x + dx.x * mm.x, xv.y + dx.y * mm.y,        \
                               xv.z + dx.z * mm.z, xv.w + dx.w * mm.w);       \
        *(float4*)(OUTP + e) = o;                                             \
    }
    APPLY(mr, o_r) APPLY(mw, o_w) APPLY(mk, o_k)
    APPLY(mv, o_v) APPLY(ma, o_a) APPLY(mg, o_g)
#undef APPLY
}

// ---------------------------------------------------------------------------
// plain f32 GEMM: C[M,N] = A[M,K] @ B[K,N].  M from grid (64/row-tile).
// BM=64 BN=64 BK=16, 256 threads, 4x4 per thread.
// ---------------------------------------------------------------------------
__global__ __launch_bounds__(256) void gemm64_kernel(
    const float* __restrict__ A, int lda,
    const float* __restrict__ Bw, int ldb,
    float* __restrict__ Cc, int ldc, int N, int K)
{
    __shared__ float As[16][68];
    __shared__ float Bs[16][64];
    int bm = blockIdx.x * 64, bn = blockIdx.y * 64;
    int tid = threadIdx.x;
    int tx = tid & 15, ty = tid >> 4;
    int ar = tid >> 2, ak = (tid & 3) * 4;
    int bkr = tid >> 4, bnc = (tid & 15) * 4;
    bool bok = (bn + bnc) < N;
    const float* Aptr = A + (size_t)(bm + ar) * lda + ak;
    const float* Bptr = Bw + (size_t)bkr * ldb + bn + bnc;
    float acc[4][4];
#pragma unroll
    for (int i = 0; i < 4; ++i)
#pragma unroll
        for (int j = 0; j < 4; ++j) acc[i][j] = 0.f;

    for (int k0 = 0; k0 < K; k0 += 16) {
        float4 a4 = *(const float4*)(Aptr + k0);
        float4 b4 = make_float4(0.f, 0.f, 0.f, 0.f);
        if (bok) b4 = *(const float4*)(Bptr + (size_t)k0 * ldb);
        As[ak + 0][ar] = a4.x;
        As[ak + 1][ar] = a4.y;
        As[ak + 2][ar] = a4.z;
        As[ak + 3][ar] = a4.w;
        *(float4*)&Bs[bkr][bnc] = b4;
        __syncthreads();
#pragma unroll
        for (int kk = 0; kk < 16; ++kk) {
            float4 av = *(const float4*)&As[kk][ty * 4];
            float4 bv = *(const float4*)&Bs[kk][tx * 4];
            float aa[4] = {av.x, av.y, av.z, av.w};
            float bb[4] = {bv.x, bv.y, bv.z, bv.w};
#pragma unroll
            for (int i = 0; i < 4; ++i)
#pragma unroll
                for (int j = 0; j < 4; ++j) acc[i][j] += aa[i] * bb[j];
        }
        __syncthreads();
    }
    if (bok) {
#pragma unroll
        for (int i = 0; i < 4; ++i) {
            int row = bm + ty * 4 + i;
            float4 st = make_float4(acc[i][0], acc[i][1], acc[i][2], acc[i][3]);
            *(float4*)(Cc + (size_t)row * ldc + bn + tx * 4) = st;
        }
    }
}

// ---------------------------------------------------------------------------
// activations on hid: cols [0,64) tanh (w), [160,288) sigmoid (g)
// ---------------------------------------------------------------------------
__global__ __launch_bounds__(256) void hidact_kernel(float* hid)
{
    int idx = blockIdx.x * 256 + threadIdx.x;
    if (idx >= Mn * 288) return;
    int c = idx % 288;
    float v = hid[idx];
    if (c < 64) v = tanhf(v);
    else if (c >= 160) v = sigmf(v);
    hid[idx] = v;
}

// ---------------------------------------------------------------------------
// elementwise stage 3: w, a, v-residual, kk-norm, kh, ah, bh.
// ---------------------------------------------------------------------------
__global__ __launch_bounds__(256) void stage3e_kernel(
    const float* wrawp, const float* aprep, const float* vsigp,
    const float* kraw, const float* vfirst,
    const float* w0, const float* a0, const float* v0c,
    const float* kkc, const float* kac,
    float* w_out, float* v_io, float* ah_out, float* bh_out, float* kh_out)
{
    int p = blockIdx.x * 4 + (threadIdx.x >> 6);
    int l = threadIdx.x & 63;
    int m = p / Hn;
    int h = p - m * Hn;
    int c = h * 64 + l;
    size_t idx = (size_t)m * Cn + c;
    float k = kraw[idx];
    float wr = w0[c] + wrawp[idx];
    float a = sigmf(a0[c] + aprep[idx]);
    float vs = sigmf(v0c[c] + vsigp[idx]);
    float v0g = v_io[idx];
    float v = v0g + (vfirst[idx] - v0g) * vs;
    float kk = k * kkc[c];
    float ss = kk * kk;
#pragma unroll
    for (int o = 32; o; o >>= 1) ss += __shfl_xor(ss, o);
    float inv = 1.0f / fmaxf(sqrtf(ss), 1e-12f);
    kk *= inv;
    float w = sigmf(wr) * 0.60653065971263342f;  // sigmoid(wr)*exp(-0.5)
    float kh = k * (1.0f + (a - 1.0f) * kac[c]);
    w_out[idx] = w;
    v_io[idx] = v;
    ah_out[idx] = -kk;
    bh_out[idx] = kk * a;
    kh_out[idx] = kh;
}

// ---------------------------------------------------------------------------
// LDS-FREE sequential WKV scan, depth-4 register ring pipeline.
// grid = B*H*4 blocks of ONE wave. Block (bh,q) owns rows [16q,16q+16).
// lane = (row=l>>2, cg=l&3) owns 16 state cols of one row. Each lane loads
// its own 16-col slices of r,w,k,a,b (+ v scalar) DIRECTLY from global
// (16-lane same-address dup = same cache lines, free). 4 register sets ring;
// loads issued 4 steps ahead of use (counted vmcnt). Quad reductions via
// DPP quad_perm (VALU latency). ZERO LDS ops, zero barriers.
// ---------------------------------------------------------------------------
__global__ __launch_bounds__(64, 1) void scan_kernel(
    const float* __restrict__ rP, const float* __restrict__ wP,
    const float* __restrict__ kP, const float* __restrict__ aP,
    const float* __restrict__ bP, const float* __restrict__ vP,
    float* __restrict__ wkv)
{
    int l = threadIdx.x;
    int blk = blockIdx.x;
    int bh = blk >> 2, q = blk & 3;
    int bb = bh / Hn, h = bh - bb * Hn;
    size_t base = (size_t)bb * Tn * Cn + h * 64;
    int rl = l >> 2, cg = l & 3;
    int c0 = cg * 16;
    int arow = q * 16 + rl;

    const float* pr = rP + base + c0;
    const float* pw = wP + base + c0;
    const float* pk = kP + base + c0;
    const float* pa = aP + base + c0;
    const float* pb = bP + base + c0;
    const float* pv = vP + base + arow;

    float s[16];
#pragma unroll
    for (int z = 0; z < 16; ++z) s[z] = 0.f;

    float* po = wkv + base + arow;

#define DECLSET(S)                                                            \
    float4 S##r[4], S##w[4], S##k[4], S##a[4], S##b[4];                       \
    float S##v;
#define LOADSET(S)                                                            \
    {                                                                         \
        _Pragma("unroll")                                                     \
        for (int j = 0; j < 4; ++j) {                                         \
            S##r[j] = *(const float4*)(pr + 4 * j);                           \
            S##w[j] = *(const float4*)(pw + 4 * j);                           \
            S##k[j] = *(const float4*)(pk + 4 * j);                           \
            S##a[j] = *(const float4*)(pa + 4 * j);                           \
            S##b[j] = *(const float4*)(pb + 4 * j);                           \
        }                                                                     \
        S##v = *pv;                                                           \
    }
#define ADVANCE(COND)                                                         \
    {                                                                         \
        int adv = (COND) ? Cn : 0;                                            \
        pr += adv; pw += adv; pk += adv; pa += adv; pb += adv; pv += adv;     \
    }
#define COMPUTE(S)                                                            \
    {                                                                         \
        float sp0 = 0.f, sp1 = 0.f, sp2 = 0.f, sp3 = 0.f;                     \
        _Pragma("unroll")                                                     \
        for (int j = 0; j < 4; ++j) {                                         \
            sp0 += s[4 * j + 0] * S##a[j].x;                                  \
            sp1 += s[4 * j + 1] * S##a[j].y;                                  \
            sp2 += s[4 * j + 2] * S##a[j].z;                                  \
            sp3 += s[4 * j + 3] * S##a[j].w;                                  \
        }                                                                     \
        float sa = quadsum((sp0 + sp1) + (sp2 + sp3));                        \
        float vi = S##v;                                                      \
        float op0 = 0.f, op1 = 0.f, op2 = 0.f, op3 = 0.f;                     \
        _Pragma("unroll")                                                     \
        for (int j = 0; j < 4; ++j) {                                         \
            s[4 * j + 0] = s[4 * j + 0] * S##w[j].x + sa * S##b[j].x + vi * S##k[j].x; \
            op0 += s[4 * j + 0] * S##r[j].x;                                  \
            s[4 * j + 1] = s[4 * j + 1] * S##w[j].y + sa * S##b[j].y + vi * S##k[j].y; \
            op1 += s[4 * j + 1] * S##r[j].y;                                  \
            s[4 * j + 2] = s[4 * j + 2] * S##w[j].z + sa * S##b[j].z + vi * S##k[j].z; \
            op2 += s[4 * j + 2] * S##r[j].z;                                  \
            s[4 * j + 3] = s[4 * j + 3] * S##w[j].w + sa * S##b[j].w + vi * S##k[j].w; \
            op3 += s[4 * j + 3] * S##r[j].w;                                  \
        }                                                                     \
        float op = quadsum((op0 + op1) + (op2 + op3));                        \
        if (cg == 0) *po = op;                                                \
        po += Cn;                                                             \
    }
    // PHASE: compute step STEP from set S (counted vmcnt — 3 newer sets
    // outstanding), then reload S with step STEP+4's data.
#define PHASE(S, STEP)                                                        \
    {                                                                         \
        COMPUTE(S)                                                            \
        LOADSET(S)                                                            \
        ADVANCE((STEP) + 5 < Tn)                                              \
    }

    DECLSET(Ra) DECLSET(Rb) DECLSET(Rc) DECLSET(Rd)
    // preload steps 0..3; pointers end at step 4
    LOADSET(Ra) ADVANCE(1)
    LOADSET(Rb) ADVANCE(1)
    LOADSET(Rc) ADVANCE(1)
    LOADSET(Rd) ADVANCE(1)

    for (int t = 0; t < Tn; t += 4) {
        PHASE(Ra, t + 0)
        PHASE(Rb, t + 1)
        PHASE(Rc, t + 2)
        PHASE(Rd, t + 3)
    }
#undef PHASE
#undef COMPUTE
#undef ADVANCE
#undef LOADSET
#undef DECLSET
}

// ---------------------------------------------------------------------------
// post-scan: per-head groupnorm + bonus + gate.  one wave per (m,h).
// ---------------------------------------------------------------------------
__global__ __launch_bounds__(256) void postnorm_kernel(
    const float* __restrict__ wkv, const float* __restrict__ rB,
    const float* __restrict__ kB, const float* __restrict__ vB,
    const float* __restrict__ gB, const float* __restrict__ r_k,
    const float* __restrict__ ln_g, const float* __restrict__ ln_b,
    float* __restrict__ xog)
{
    int grp = blockIdx.x * 4 + (threadIdx.x >> 6);
    int l = threadIdx.x & 63;
    int m = grp / Hn, h = grp - m * Hn;
    int c = h * 64 + l;
    size_t idx = (size_t)m * Cn + c;
    float out = wkv[idx];
    float rv = rB[idx], kv = kB[idx], vv = vB[idx];
    float m1 = out, m2 = out * out, bd = rv * kv * r_k[c];
#pragma unroll
    for (int o = 32; o; o >>= 1) {
        m1 += __shfl_xor(m1, o);
        m2 += __shfl_xor(m2, o);
        bd += __shfl_xor(bd, o);
    }
    float mean = m1 * (1.f / 64.f);
    float var = m2 * (1.f / 64.f) - mean * mean;
    float xn = (out - mean) * rsqrtf(var + 0.00064f) * ln_g[c] + ln_b[c];
    xog[idx] = (xn + bd * vv) * gB[idx];
}

// ---------------------------------------------------------------------------
extern "C" void kernel_launch(void* const* d_in, const int* in_sizes, int n_in,
                              void* d_out, int out_size, void* d_ws, size_t ws_size,
                              hipStream_t stream)
{
    const float* x       = (const float*)d_in[0];
    const float* v_first = (const float*)d_in[1];
    const float* x_r     = (const float*)d_in[2];
    const float* x_w     = (const float*)d_in[3];
    const float* x_k     = (const float*)d_in[4];
    const float* x_v     = (const float*)d_in[5];
    const float* x_a     = (const float*)d_in[6];
    const float* x_g     = (const float*)d_in[7];
    const float* w0      = (const float*)d_in[8];
    const float* w1      = (const float*)d_in[9];
    const float* w2      = (const float*)d_in[10];
    const float* a0      = (const float*)d_in[11];
    const float* a1      = (const float*)d_in[12];
    const float* a2      = (const float*)d_in[13];
    const float* v0c     = (const float*)d_in[14];
    const float* v1      = (const float*)d_in[15];
    const float* v2      = (const float*)d_in[16];
    const float* g1w     = (const float*)d_in[17];
    const float* g2w     = (const float*)d_in[18];
    const float* k_k     = (const float*)d_in[19];
    const float* k_a     = (const float*)d_in[20];
    const float* r_k     = (const float*)d_in[21];
    const float* Wr      = (const float*)d_in[22];
    const float* Wk      = (const float*)d_in[23];
    const float* Wv      = (const float*)d_in[24];
    const float* Wo      = (const float*)d_in[25];
    const float* ln_g    = (const float*)d_in[26];
    const float* ln_b    = (const float*)d_in[27];
    float* out = (float*)d_out;

    float* ws = (float*)d_ws;
    size_t MC = (size_t)Mn * Cn;
    float* B0 = ws + 0 * MC;  // xr -> wraw -> ah
    float* B1 = ws + 1 * MC;  // xw -> w    -> xog
    float* B2 = ws + 2 * MC;  // xk -> apre -> bh
    float* B3 = ws + 3 * MC;  // xv -> vsigp -> kh
    float* B4 = ws + 4 * MC;  // xa -> wkv (raw scan out)
    float* B5 = ws + 5 * MC;  // xg -> g
    float* B6 = ws + 6 * MC;  // r
    float* B7 = ws + 7 * MC;  // k (raw)
    float* B8 = ws + 8 * MC;  // v0 -> v
    float* hid = ws + 9 * MC; // [Mn,288]

    mix6_kernel<<<3840, 256, 0, stream>>>(x, x_r, x_w, x_k, x_v, x_a, x_g,
                                          B0, B1, B2, B3, B4, B5);

    dim3 gBig(64, 15);
    // stage 1: big projections
    gemm64_kernel<<<gBig, 256, 0, stream>>>(B0, Cn, Wr, Cn, B6, Cn, Cn, Cn);
    gemm64_kernel<<<gBig, 256, 0, stream>>>(B2, Cn, Wk, Cn, B7, Cn, Cn, Cn);
    gemm64_kernel<<<gBig, 256, 0, stream>>>(B3, Cn, Wv, Cn, B8, Cn, Cn, Cn);
    // stage 2: lora-down GEMMs into hid
    dim3 g64(64, 1);
    gemm64_kernel<<<g64, 256, 0, stream>>>(B1, Cn, w1, 64, hid + 0, 288, 64, Cn);
    gemm64_kernel<<<g64, 256, 0, stream>>>(B4, Cn, a1, 64, hid + 64, 288, 64, Cn);
    gemm64_kernel<<<g64, 256, 0, stream>>>(B3, Cn, v1, 32, hid + 128, 288, 32, Cn);
    gemm64_kernel<<<dim3(64, 2), 256, 0, stream>>>(B5, Cn, g1w, 128, hid + 160, 288, 128, Cn);
    hidact_kernel<<<4608, 256, 0, stream>>>(hid);
    // stage 3: lora-up GEMMs
    gemm64_kernel<<<gBig, 256, 0, stream>>>(hid + 0, 288, w2, Cn, B0, Cn, Cn, 64);
    gemm64_kernel<<<gBig, 256, 0, stream>>>(hid + 64, 288, a2, Cn, B2, Cn, Cn, 64);
    gemm64_kernel<<<gBig, 256, 0, stream>>>(hid + 128, 288, v2, Cn, B3, Cn, Cn, 32);
    gemm64_kernel<<<gBig, 256, 0, stream>>>(hid + 160, 288, g2w, Cn, B5, Cn, Cn, 128);
    // stage 3e: elementwise + head-norm
    stage3e_kernel<<<15360, 256, 0, stream>>>(B0, B2, B3, B7, v_first,
                                              w0, a0, v0c, k_k, k_a,
                                              B1, B8, B0, B2, B3);
    // stage 4: LDS-free depth-4 register-pipelined scan (raw wkv out)
    scan_kernel<<<240, 64, 0, stream>>>(B6, B1, B3, B0, B2, B8, B4);
    // stage 4b: groupnorm + bonus + gate
    postnorm_kernel<<<15360, 256, 0, stream>>>(B4, B6, B3, B8, B5,
                                               r_k, ln_g, ln_b, B1);
    // stage 5: output projection
    gemm64_kernel<<<gBig, 256, 0, stream>>>(B1, Cn, Wo, Cn, out, Cn, Cn, Cn);
}

// Round 6
// 1070.371 us; speedup vs baseline: 1.2253x; 1.2078x over previous
//
#include <hip/hip_runtime.h>
#include <hip/hip_bf16.h>
#include <math.h>

#define Tn 1024
#define Cn 960
#define Hn 15
#define Nn 64
#define Mn 4096  // B*T

__device__ __forceinline__ float sigmf(float x) { return 1.0f / (1.0f + __expf(-x)); }

// quad-lane (xor1 + xor2) sum via DPP quad_perm — VALU latency, no DS ops.
__device__ __forceinline__ float quadsum(float x) {
    int xi = __float_as_int(x);
    int y1 = __builtin_amdgcn_update_dpp(0, xi, 0xB1, 0xF, 0xF, true);  // [1,0,3,2]
    x += __int_as_float(y1);
    xi = __float_as_int(x);
    int y2 = __builtin_amdgcn_update_dpp(0, xi, 0x4E, 0xF, 0xF, true);  // [2,3,0,1]
    x += __int_as_float(y2);
    return x;
}

// ---------------------------------------------------------------------------
// token-shift + 6 mixes: out_j = x + (shift(x) - x) * mix_j
// ---------------------------------------------------------------------------
__global__ __launch_bounds__(256) void mix6_kernel(
    const float* __restrict__ x,
    const float* __restrict__ mr, const float* __restrict__ mw, const float* __restrict__ mk,
    const float* __restrict__ mv, const float* __restrict__ ma, const float* __restrict__ mg,
    float* __restrict__ o_r, float* __restrict__ o_w, float* __restrict__ o_k,
    float* __restrict__ o_v, float* __restrict__ o_a, float* __restrict__ o_g)
{
    int idx = blockIdx.x * 256 + threadIdx.x;  // float4 index
    int e = idx * 4;
    if (e >= Mn * Cn) return;
    int m = e / Cn;
    int c = e - m * Cn;
    int t = m & (Tn - 1);
    float4 xv = *(const float4*)(x + e);
    float4 xp = make_float4(0.f, 0.f, 0.f, 0.f);
    if (t > 0) xp = *(const float4*)(x + e - Cn);
    float4 dx = make_float4(xp.x - xv.x, xp.y - xv.y, xp.z - xv.z, xp.w - xv.w);
#define APPLY(MIXP, OUTP)                                                     \
    {                                                                         \
        float4 mm = *(const float4*)(MIXP + c);                               \
        float4 o = make_float4(xv.x + dx.x * mm.x, xv.y + dx.y * mm.y,        \
                               xv.z + dx.z * mm.z, xv.w + dx.w * mm.w);       \
        *(float4*)(OUTP + e) = o;                                             \
    }
    APPLY(mr, o_r) APPLY(mw, o_w) APPLY(mk, o_k)
    APPLY(mv, o_v) APPLY(ma, o_a) APPLY(mg, o_g)
#undef APPLY
}

// ---------------------------------------------------------------------------
// plain f32 GEMM: C[M,N] = A[M,K] @ B[K,N].  M from grid (64/row-tile).
// BM=64 BN=64 BK=16, 256 threads, 4x4 per thread.
// ---------------------------------------------------------------------------
__global__ __launch_bounds__(256) void gemm64_kernel(
    const float* __restrict__ A, int lda,
    const float* __restrict__ Bw, int ldb,
    float* __restrict__ Cc, int ldc, int N, int K)
{
    __shared__ float As[16][68];
    __shared__ float Bs[16][64];
    int bm = blockIdx.x * 64, bn = blockIdx.y * 64;
    int tid = threadIdx.x;
    int tx = tid & 15, ty = tid >> 4;
    int ar = tid >> 2, ak = (tid & 3) * 4;
    int bkr = tid >> 4, bnc = (tid & 15) * 4;
    bool bok = (bn + bnc) < N;
    const float* Aptr = A + (size_t)(bm + ar) * lda + ak;
    const float* Bptr = Bw + (size_t)bkr * ldb + bn + bnc;
    float acc[4][4];
#pragma unroll
    for (int i = 0; i < 4; ++i)
#pragma unroll
        for (int j = 0; j < 4; ++j) acc[i][j] = 0.f;

    for (int k0 = 0; k0 < K; k0 += 16) {
        float4 a4 = *(const float4*)(Aptr + k0);
        float4 b4 = make_float4(0.f, 0.f, 0.f, 0.f);
        if (bok) b4 = *(const float4*)(Bptr + (size_t)k0 * ldb);
        As[ak + 0][ar] = a4.x;
        As[ak + 1][ar] = a4.y;
        As[ak + 2][ar] = a4.z;
        As[ak + 3][ar] = a4.w;
        *(float4*)&Bs[bkr][bnc] = b4;
        __syncthreads();
#pragma unroll
        for (int kk = 0; kk < 16; ++kk) {
            float4 av = *(const float4*)&As[kk][ty * 4];
            float4 bv = *(const float4*)&Bs[kk][tx * 4];
            float aa[4] = {av.x, av.y, av.z, av.w};
            float bb[4] = {bv.x, bv.y, bv.z, bv.w};
#pragma unroll
            for (int i = 0; i < 4; ++i)
#pragma unroll
                for (int j = 0; j < 4; ++j) acc[i][j] += aa[i] * bb[j];
        }
        __syncthreads();
    }
    if (bok) {
#pragma unroll
        for (int i = 0; i < 4; ++i) {
            int row = bm + ty * 4 + i;
            float4 st = make_float4(acc[i][0], acc[i][1], acc[i][2], acc[i][3]);
            *(float4*)(Cc + (size_t)row * ldc + bn + tx * 4) = st;
        }
    }
}

// ---------------------------------------------------------------------------
// activations on hid: cols [0,64) tanh (w), [160,288) sigmoid (g)
// ---------------------------------------------------------------------------
__global__ __launch_bounds__(256) void hidact_kernel(float* hid)
{
    int idx = blockIdx.x * 256 + threadIdx.x;
    if (idx >= Mn * 288) return;
    int c = idx % 288;
    float v = hid[idx];
    if (c < 64) v = tanhf(v);
    else if (c >= 160) v = sigmf(v);
    hid[idx] = v;
}

// ---------------------------------------------------------------------------
// elementwise stage 3: w, a, v-residual, kk-norm, kh, ah, bh.
// ---------------------------------------------------------------------------
__global__ __launch_bounds__(256) void stage3e_kernel(
    const float* wrawp, const float* aprep, const float* vsigp,
    const float* kraw, const float* vfirst,
    const float* w0, const float* a0, const float* v0c,
    const float* kkc, const float* kac,
    float* w_out, float* v_io, float* ah_out, float* bh_out, float* kh_out)
{
    int p = blockIdx.x * 4 + (threadIdx.x >> 6);
    int l = threadIdx.x & 63;
    int m = p / Hn;
    int h = p - m * Hn;
    int c = h * 64 + l;
    size_t idx = (size_t)m * Cn + c;
    float k = kraw[idx];
    float wr = w0[c] + wrawp[idx];
    float a = sigmf(a0[c] + aprep[idx]);
    float vs = sigmf(v0c[c] + vsigp[idx]);
    float v0g = v_io[idx];
    float v = v0g + (vfirst[idx] - v0g) * vs;
    float kk = k * kkc[c];
    float ss = kk * kk;
#pragma unroll
    for (int o = 32; o; o >>= 1) ss += __shfl_xor(ss, o);
    float inv = 1.0f / fmaxf(sqrtf(ss), 1e-12f);
    kk *= inv;
    float w = sigmf(wr) * 0.60653065971263342f;  // sigmoid(wr)*exp(-0.5)
    float kh = k * (1.0f + (a - 1.0f) * kac[c]);
    w_out[idx] = w;
    v_io[idx] = v;
    ah_out[idx] = -kk;
    bh_out[idx] = kk * a;
    kh_out[idx] = kh;
}

// ---------------------------------------------------------------------------
// CHUNKED sequential WKV scan. One block of 256 threads (4 waves) per (b,h)
// chain; wave q owns rows [16q,16q+16), lane = (rl=l>>2, cg=l&3) owns 16
// state cols of one row. T processed in chunks of 16 steps:
//  - chunk c+1's inputs loaded to REGISTERS at top of chunk c (coalesced),
//    ds_written to the other LDS half at chunk end -> ONE lgkm+barrier per
//    16 steps; global latency hidden under ~4000 cyc of compute.
//  - per-step vectors ds_read one step ahead into alternating register sets
//    (A/B) so LDS latency is off the critical path.
//  - quad reductions via DPP (VALU latency, no DS).
// ---------------------------------------------------------------------------
__global__ __launch_bounds__(256, 1) void scan_kernel(
    const float* __restrict__ rP, const float* __restrict__ wP,
    const float* __restrict__ kP, const float* __restrict__ aP,
    const float* __restrict__ bP, const float* __restrict__ vP,
    float* __restrict__ wkv)
{
    __shared__ float buf[2][6][16][64];  // 48 KB: [half][r,w,k,a,b,v][step][64]
    int tid = threadIdx.x;
    int q = tid >> 6, l = tid & 63;
    int bh = blockIdx.x;
    int bb = bh / Hn, h = bh - bb * Hn;
    size_t base = (size_t)bb * Tn * Cn + h * 64;
    int rl = l >> 2, cg = l & 3;
    int c0 = cg * 16;
    int arow = q * 16 + rl;

    // staging source pointers: thread stages row (tid>>4) of each chunk,
    // 16B segment (tid&15)
    size_t soff = base + (size_t)(tid >> 4) * Cn + (tid & 15) * 4;
    const float* pSr = rP + soff;
    const float* pSw = wP + soff;
    const float* pSk = kP + soff;
    const float* pSa = aP + soff;
    const float* pSb = bP + soff;
    const float* pSv = vP + soff;
    int wofs = (tid >> 4) * 64 + (tid & 15) * 4;  // LDS write offset (floats)

    float s[16];
#pragma unroll
    for (int z = 0; z < 16; ++z) s[z] = 0.f;

    float* po = wkv + base + arow;

    // ---- stage chunk 0 into buf[0]
    {
        float4 h0 = *(const float4*)(pSr);
        float4 h1 = *(const float4*)(pSw);
        float4 h2 = *(const float4*)(pSk);
        float4 h3 = *(const float4*)(pSa);
        float4 h4 = *(const float4*)(pSb);
        float4 h5 = *(const float4*)(pSv);
        float* bn = &buf[0][0][0][0];
        *(float4*)(bn + 0 * 1024 + wofs) = h0;
        *(float4*)(bn + 1 * 1024 + wofs) = h1;
        *(float4*)(bn + 2 * 1024 + wofs) = h2;
        *(float4*)(bn + 3 * 1024 + wofs) = h3;
        *(float4*)(bn + 4 * 1024 + wofs) = h4;
        *(float4*)(bn + 5 * 1024 + wofs) = h5;
        asm volatile("s_waitcnt lgkmcnt(0)" ::: "memory");
        __builtin_amdgcn_s_barrier();
    }

#define DECLSET(S)                                                            \
    float4 S##r[4], S##w[4], S##k[4], S##a[4], S##b[4];                       \
    float S##v;
#define DSLOAD(S, T)                                                          \
    {                                                                         \
        _Pragma("unroll")                                                     \
        for (int j = 0; j < 4; ++j) {                                         \
            S##r[j] = *(const float4*)(bc + 0 * 1024 + (T) * 64 + c0 + 4 * j);\
            S##w[j] = *(const float4*)(bc + 1 * 1024 + (T) * 64 + c0 + 4 * j);\
            S##k[j] = *(const float4*)(bc + 2 * 1024 + (T) * 64 + c0 + 4 * j);\
            S##a[j] = *(const float4*)(bc + 3 * 1024 + (T) * 64 + c0 + 4 * j);\
            S##b[j] = *(const float4*)(bc + 4 * 1024 + (T) * 64 + c0 + 4 * j);\
        }                                                                     \
        S##v = bc[5 * 1024 + (T) * 64 + arow];                                \
    }
#define COMPUTE(S)                                                            \
    {                                                                         \
        float sp0 = 0.f, sp1 = 0.f, sp2 = 0.f, sp3 = 0.f;                     \
        _Pragma("unroll")                                                     \
        for (int j = 0; j < 4; ++j) {                                         \
            sp0 += s[4 * j + 0] * S##a[j].x;                                  \
            sp1 += s[4 * j + 1] * S##a[j].y;                                  \
            sp2 += s[4 * j + 2] * S##a[j].z;                                  \
            sp3 += s[4 * j + 3] * S##a[j].w;                                  \
        }                                                                     \
        float sa = quadsum((sp0 + sp1) + (sp2 + sp3));                        \
        float vi = S##v;                                                      \
        float op0 = 0.f, op1 = 0.f, op2 = 0.f, op3 = 0.f;                     \
        _Pragma("unroll")                                                     \
        for (int j = 0; j < 4; ++j) {                                         \
            s[4 * j + 0] = s[4 * j + 0] * S##w[j].x + sa * S##b[j].x + vi * S##k[j].x; \
            op0 += s[4 * j + 0] * S##r[j].x;                                  \
            s[4 * j + 1] = s[4 * j + 1] * S##w[j].y + sa * S##b[j].y + vi * S##k[j].y; \
            op1 += s[4 * j + 1] * S##r[j].y;                                  \
            s[4 * j + 2] = s[4 * j + 2] * S##w[j].z + sa * S##b[j].z + vi * S##k[j].z; \
            op2 += s[4 * j + 2] * S##r[j].z;                                  \
            s[4 * j + 3] = s[4 * j + 3] * S##w[j].w + sa * S##b[j].w + vi * S##k[j].w; \
            op3 += s[4 * j + 3] * S##r[j].w;                                  \
        }                                                                     \
        float op = quadsum((op0 + op1) + (op2 + op3));                        \
        if (cg == 0) *po = op;                                                \
        po += Cn;                                                             \
    }

    DECLSET(A) DECLSET(B)

    int cur = 0;
    for (int c = 0; c < 64; ++c) {
        const float* bc = &buf[cur][0][0][0];
        // issue staging loads for chunk c+1 (clamped; c=63 redundant, unread)
        size_t t2 = (size_t)((c < 63 ? c + 1 : 63) * 16) * Cn;
        float4 g0 = *(const float4*)(pSr + t2);
        float4 g1 = *(const float4*)(pSw + t2);
        float4 g2 = *(const float4*)(pSk + t2);
        float4 g3 = *(const float4*)(pSa + t2);
        float4 g4 = *(const float4*)(pSb + t2);
        float4 g5 = *(const float4*)(pSv + t2);

        // 16 steps, one-step-ahead LDS->reg prefetch
        DSLOAD(A, 0)
#pragma unroll
        for (int it = 0; it < 8; ++it) {
            DSLOAD(B, 2 * it + 1)
            COMPUTE(A)
            if (it < 7) { DSLOAD(A, 2 * it + 2) }
            COMPUTE(B)
        }

        // park staged regs into the other LDS half (compiler inserts the
        // vmcnt waits for g*), then one barrier per chunk.
        float* bn = &buf[cur ^ 1][0][0][0];
        *(float4*)(bn + 0 * 1024 + wofs) = g0;
        *(float4*)(bn + 1 * 1024 + wofs) = g1;
        *(float4*)(bn + 2 * 1024 + wofs) = g2;
        *(float4*)(bn + 3 * 1024 + wofs) = g3;
        *(float4*)(bn + 4 * 1024 + wofs) = g4;
        *(float4*)(bn + 5 * 1024 + wofs) = g5;
        asm volatile("s_waitcnt lgkmcnt(0)" ::: "memory");
        __builtin_amdgcn_s_barrier();
        cur ^= 1;
    }
#undef COMPUTE
#undef DSLOAD
#undef DECLSET
}

// ---------------------------------------------------------------------------
// post-scan: per-head groupnorm + bonus + gate.  one wave per (m,h).
// ---------------------------------------------------------------------------
__global__ __launch_bounds__(256) void postnorm_kernel(
    const float* __restrict__ wkv, const float* __restrict__ rB,
    const float* __restrict__ kB, const float* __restrict__ vB,
    const float* __restrict__ gB, const float* __restrict__ r_k,
    const float* __restrict__ ln_g, const float* __restrict__ ln_b,
    float* __restrict__ xog)
{
    int grp = blockIdx.x * 4 + (threadIdx.x >> 6);
    int l = threadIdx.x & 63;
    int m = grp / Hn, h = grp - m * Hn;
    int c = h * 64 + l;
    size_t idx = (size_t)m * Cn + c;
    float out = wkv[idx];
    float rv = rB[idx], kv = kB[idx], vv = vB[idx];
    float m1 = out, m2 = out * out, bd = rv * kv * r_k[c];
#pragma unroll
    for (int o = 32; o; o >>= 1) {
        m1 += __shfl_xor(m1, o);
        m2 += __shfl_xor(m2, o);
        bd += __shfl_xor(bd, o);
    }
    float mean = m1 * (1.f / 64.f);
    float var = m2 * (1.f / 64.f) - mean * mean;
    float xn = (out - mean) * rsqrtf(var + 0.00064f) * ln_g[c] + ln_b[c];
    xog[idx] = (xn + bd * vv) * gB[idx];
}

// ---------------------------------------------------------------------------
extern "C" void kernel_launch(void* const* d_in, const int* in_sizes, int n_in,
                              void* d_out, int out_size, void* d_ws, size_t ws_size,
                              hipStream_t stream)
{
    const float* x       = (const float*)d_in[0];
    const float* v_first = (const float*)d_in[1];
    const float* x_r     = (const float*)d_in[2];
    const float* x_w     = (const float*)d_in[3];
    const float* x_k     = (const float*)d_in[4];
    const float* x_v     = (const float*)d_in[5];
    const float* x_a     = (const float*)d_in[6];
    const float* x_g     = (const float*)d_in[7];
    const float* w0      = (const float*)d_in[8];
    const float* w1      = (const float*)d_in[9];
    const float* w2      = (const float*)d_in[10];
    const float* a0      = (const float*)d_in[11];
    const float* a1      = (const float*)d_in[12];
    const float* a2      = (const float*)d_in[13];
    const float* v0c     = (const float*)d_in[14];
    const float* v1      = (const float*)d_in[15];
    const float* v2      = (const float*)d_in[16];
    const float* g1w     = (const float*)d_in[17];
    const float* g2w     = (const float*)d_in[18];
    const float* k_k     = (const float*)d_in[19];
    const float* k_a     = (const float*)d_in[20];
    const float* r_k     = (const float*)d_in[21];
    const float* Wr      = (const float*)d_in[22];
    const float* Wk      = (const float*)d_in[23];
    const float* Wv      = (const float*)d_in[24];
    const float* Wo      = (const float*)d_in[25];
    const float* ln_g    = (const float*)d_in[26];
    const float* ln_b    = (const float*)d_in[27];
    float* out = (float*)d_out;

    float* ws = (float*)d_ws;
    size_t MC = (size_t)Mn * Cn;
    float* B0 = ws + 0 * MC;  // xr -> wraw -> ah
    float* B1 = ws + 1 * MC;  // xw -> w    -> xog
    float* B2 = ws + 2 * MC;  // xk -> apre -> bh
    float* B3 = ws + 3 * MC;  // xv -> vsigp -> kh
    float* B4 = ws + 4 * MC;  // xa -> wkv (raw scan out)
    float* B5 = ws + 5 * MC;  // xg -> g
    float* B6 = ws + 6 * MC;  // r
    float* B7 = ws + 7 * MC;  // k (raw)
    float* B8 = ws + 8 * MC;  // v0 -> v
    float* hid = ws + 9 * MC; // [Mn,288]

    mix6_kernel<<<3840, 256, 0, stream>>>(x, x_r, x_w, x_k, x_v, x_a, x_g,
                                          B0, B1, B2, B3, B4, B5);

    dim3 gBig(64, 15);
    // stage 1: big projections
    gemm64_kernel<<<gBig, 256, 0, stream>>>(B0, Cn, Wr, Cn, B6, Cn, Cn, Cn);
    gemm64_kernel<<<gBig, 256, 0, stream>>>(B2, Cn, Wk, Cn, B7, Cn, Cn, Cn);
    gemm64_kernel<<<gBig, 256, 0, stream>>>(B3, Cn, Wv, Cn, B8, Cn, Cn, Cn);
    // stage 2: lora-down GEMMs into hid
    dim3 g64(64, 1);
    gemm64_kernel<<<g64, 256, 0, stream>>>(B1, Cn, w1, 64, hid + 0, 288, 64, Cn);
    gemm64_kernel<<<g64, 256, 0, stream>>>(B4, Cn, a1, 64, hid + 64, 288, 64, Cn);
    gemm64_kernel<<<g64, 256, 0, stream>>>(B3, Cn, v1, 32, hid + 128, 288, 32, Cn);
    gemm64_kernel<<<dim3(64, 2), 256, 0, stream>>>(B5, Cn, g1w, 128, hid + 160, 288, 128, Cn);
    hidact_kernel<<<4608, 256, 0, stream>>>(hid);
    // stage 3: lora-up GEMMs
    gemm64_kernel<<<gBig, 256, 0, stream>>>(hid + 0, 288, w2, Cn, B0, Cn, Cn, 64);
    gemm64_kernel<<<gBig, 256, 0, stream>>>(hid + 64, 288, a2, Cn, B2, Cn, Cn, 64);
    gemm64_kernel<<<gBig, 256, 0, stream>>>(hid + 128, 288, v2, Cn, B3, Cn, Cn, 32);
    gemm64_kernel<<<gBig, 256, 0, stream>>>(hid + 160, 288, g2w, Cn, B5, Cn, Cn, 128);
    // stage 3e: elementwise + head-norm
    stage3e_kernel<<<15360, 256, 0, stream>>>(B0, B2, B3, B7, v_first,
                                              w0, a0, v0c, k_k, k_a,
                                              B1, B8, B0, B2, B3);
    // stage 4: chunked scan (raw wkv out)
    scan_kernel<<<60, 256, 0, stream>>>(B6, B1, B3, B0, B2, B8, B4);
    // stage 4b: groupnorm + bonus + gate
    postnorm_kernel<<<15360, 256, 0, stream>>>(B4, B6, B3, B8, B5,
                                               r_k, ln_g, ln_b, B1);
    // stage 5: output projection
    gemm64_kernel<<<gBig, 256, 0, stream>>>(B1, Cn, Wo, Cn, out, Cn, Cn, Cn);
}

// Round 7
// 812.256 us; speedup vs baseline: 1.6147x; 1.3178x over previous
//
#include <hip/hip_runtime.h>
#include <hip/hip_bf16.h>
#include <math.h>

#define Tn 1024
#define Cn 960
#define Hn 15
#define Nn 64
#define Mn 4096  // B*T

typedef short bf16x8 __attribute__((ext_vector_type(8)));
typedef float f32x4 __attribute__((ext_vector_type(4)));

__device__ __forceinline__ float sigmf(float x) { return 1.0f / (1.0f + __expf(-x)); }

// round-to-nearest-even f32 -> bf16 (as ushort)
__device__ __forceinline__ ushort f2bf(float x) {
    unsigned u = __float_as_uint(x);
    unsigned r = (u + 0x7FFFu + ((u >> 16) & 1u)) >> 16;
    return (ushort)r;
}
__device__ __forceinline__ float bf2f(ushort h) { return __uint_as_float(((unsigned)h) << 16); }

// quad-lane (xor1 + xor2) sum via DPP quad_perm — VALU latency, no DS ops.
__device__ __forceinline__ float quadsum(float x) {
    int xi = __float_as_int(x);
    int y1 = __builtin_amdgcn_update_dpp(0, xi, 0xB1, 0xF, 0xF, true);  // [1,0,3,2]
    x += __int_as_float(y1);
    xi = __float_as_int(x);
    int y2 = __builtin_amdgcn_update_dpp(0, xi, 0x4E, 0xF, 0xF, true);  // [2,3,0,1]
    x += __int_as_float(y2);
    return x;
}

// ---------------------------------------------------------------------------
// token-shift + 6 mixes: out_j = x + (shift(x) - x) * mix_j
// ---------------------------------------------------------------------------
__global__ __launch_bounds__(256) void mix6_kernel(
    const float* __restrict__ x,
    const float* __restrict__ mr, const float* __restrict__ mw, const float* __restrict__ mk,
    const float* __restrict__ mv, const float* __restrict__ ma, const float* __restrict__ mg,
    float* __restrict__ o_r, float* __restrict__ o_w, float* __restrict__ o_k,
    float* __restrict__ o_v, float* __restrict__ o_a, float* __restrict__ o_g)
{
    int idx = blockIdx.x * 256 + threadIdx.x;  // float4 index
    int e = idx * 4;
    if (e >= Mn * Cn) return;
    int m = e / Cn;
    int c = e - m * Cn;
    int t = m & (Tn - 1);
    float4 xv = *(const float4*)(x + e);
    float4 xp = make_float4(0.f, 0.f, 0.f, 0.f);
    if (t > 0) xp = *(const float4*)(x + e - Cn);
    float4 dx = make_float4(xp.x - xv.x, xp.y - xv.y, xp.z - xv.z, xp.w - xv.w);
#define APPLY(MIXP, OUTP)                                                     \
    {                                                                         \
        float4 mm = *(const float4*)(MIXP + c);                               \
        float4 o = make_float4(xv.x + dx.x * mm.x, xv.y + dx.y * mm.y,        \
                               xv.z + dx.z * mm.z, xv.w + dx.w * mm.w);       \
        *(float4*)(OUTP + e) = o;                                             \
    }
    APPLY(mr, o_r) APPLY(mw, o_w) APPLY(mk, o_k)
    APPLY(mv, o_v) APPLY(ma, o_a) APPLY(mg, o_g)
#undef APPLY
}

// ---------------------------------------------------------------------------
// split-convert activation: f32 [Mn][Cn] -> hi/lo bf16 (ushort) arrays
// ---------------------------------------------------------------------------
__global__ __launch_bounds__(256) void convA_kernel(
    const float* __restrict__ X, ushort* __restrict__ hi, ushort* __restrict__ lo)
{
    int idx = blockIdx.x * 256 + threadIdx.x;
    int e = idx * 4;
    if (e >= Mn * Cn) return;
    float4 x = *(const float4*)(X + e);
    ushort h0 = f2bf(x.x), h1 = f2bf(x.y), h2 = f2bf(x.z), h3 = f2bf(x.w);
    ushort l0 = f2bf(x.x - bf2f(h0)), l1 = f2bf(x.y - bf2f(h1));
    ushort l2 = f2bf(x.z - bf2f(h2)), l3 = f2bf(x.w - bf2f(h3));
    ushort4 hv = make_ushort4(h0, h1, h2, h3);
    ushort4 lv = make_ushort4(l0, l1, l2, l3);
    *(ushort4*)(hi + e) = hv;
    *(ushort4*)(lo + e) = lv;
}

// ---------------------------------------------------------------------------
// transpose + split-convert weight: W f32 [K=960][N=960] -> Thi/Tlo bf16 [N][K]
// ---------------------------------------------------------------------------
__global__ __launch_bounds__(256) void convWT_kernel(
    const float* __restrict__ W, ushort* __restrict__ Thi, ushort* __restrict__ Tlo)
{
    __shared__ float tile[32][33];
    int k0 = blockIdx.x * 32, n0 = blockIdx.y * 32;
    int tx = threadIdx.x & 31, ty = threadIdx.x >> 5;  // 32 x 8
#pragma unroll
    for (int i = 0; i < 4; ++i)
        tile[ty + 8 * i][tx] = W[(size_t)(k0 + ty + 8 * i) * 960 + n0 + tx];
    __syncthreads();
#pragma unroll
    for (int i = 0; i < 4; ++i) {
        float x = tile[tx][ty + 8 * i];
        ushort h = f2bf(x);
        ushort l = f2bf(x - bf2f(h));
        size_t o = (size_t)(n0 + ty + 8 * i) * 960 + k0 + tx;
        Thi[o] = h;
        Tlo[o] = l;
    }
}

// ---------------------------------------------------------------------------
// split-bf16 MFMA GEMM: C[M,N] = A[M,K] @ W[K,N], K=960, via
// Ahi@Whi + Ahi@Wlo + Alo@Whi  (lo*lo dropped, ~2^-18 relative).
// A*: bf16 [M][960] row-major.  B*: bf16 [N][960] (W transposed).
// BM=128 BN=64 BK=32, 256 thr (4 waves); wave q owns rows [32q,32q+32):
// 2x4 frags of 16x16, 24 mfma_16x16x32 per k-step. LDS rows padded to 80B
// (bank spread <=2-way). Double-buffered, reg-staged, 1 barrier/k-step.
// ---------------------------------------------------------------------------
__global__ __launch_bounds__(256) void gemm_bf3_kernel(
    const ushort* __restrict__ Ahi, const ushort* __restrict__ Alo,
    const ushort* __restrict__ Bhi, const ushort* __restrict__ Blo,
    float* __restrict__ C, int ldc)
{
    __shared__ __align__(16) ushort sA[2][2][128][40];  // [buf][hi/lo][row][pad40]
    __shared__ __align__(16) ushort sB[2][2][64][40];
    const int K = 960;
    int bm = blockIdx.x * 128, bn = blockIdx.y * 64;
    int t = threadIdx.x;
    int q = t >> 6, l = t & 63;
    int lr = l & 15, lk = l >> 4;  // frag row/col selector, k-chunk

    // staging assignment
    int ar = t >> 1, aseg = t & 1;                       // A: 2 thr/row, 32B segs
    int br = t & 63, bhalf = (t >> 6) & 1, bseg = t >> 7;  // B: 4 thr/row
    const ushort* gAh = Ahi + (size_t)(bm + ar) * K + aseg * 16;
    const ushort* gAl = Alo + (size_t)(bm + ar) * K + aseg * 16;
    const ushort* gB = (bhalf ? Blo : Bhi) + (size_t)(bn + br) * K + bseg * 16;

    f32x4 acc[2][4];
#pragma unroll
    for (int i = 0; i < 2; ++i)
#pragma unroll
        for (int j = 0; j < 4; ++j)
#pragma unroll
            for (int e = 0; e < 4; ++e) acc[i][j][e] = 0.f;

    float4 rh0, rh1, rl0, rl1, rb0, rb1;
#define LOADK(KOFF)                                                           \
    {                                                                         \
        rh0 = *(const float4*)(gAh + (KOFF));                                 \
        rh1 = *(const float4*)(gAh + (KOFF) + 8);                             \
        rl0 = *(const float4*)(gAl + (KOFF));                                 \
        rl1 = *(const float4*)(gAl + (KOFF) + 8);                             \
        rb0 = *(const float4*)(gB + (KOFF));                                  \
        rb1 = *(const float4*)(gB + (KOFF) + 8);                              \
    }
#define WRITEK(BUF)                                                           \
    {                                                                         \
        *(float4*)&sA[BUF][0][ar][aseg * 16] = rh0;                           \
        *(float4*)&sA[BUF][0][ar][aseg * 16 + 8] = rh1;                       \
        *(float4*)&sA[BUF][1][ar][aseg * 16] = rl0;                           \
        *(float4*)&sA[BUF][1][ar][aseg * 16 + 8] = rl1;                       \
        *(float4*)&sB[BUF][bhalf][br][bseg * 16] = rb0;                       \
        *(float4*)&sB[BUF][bhalf][br][bseg * 16 + 8] = rb1;                   \
    }
#define COMPUTEK(BUF)                                                         \
    {                                                                         \
        bf16x8 ah[2], al[2], bh[4], bl[4];                                    \
        _Pragma("unroll")                                                     \
        for (int i = 0; i < 2; ++i) {                                         \
            ah[i] = *(const bf16x8*)&sA[BUF][0][32 * q + 16 * i + lr][lk * 8];\
            al[i] = *(const bf16x8*)&sA[BUF][1][32 * q + 16 * i + lr][lk * 8];\
        }                                                                     \
        _Pragma("unroll")                                                     \
        for (int j = 0; j < 4; ++j) {                                         \
            bh[j] = *(const bf16x8*)&sB[BUF][0][16 * j + lr][lk * 8];         \
            bl[j] = *(const bf16x8*)&sB[BUF][1][16 * j + lr][lk * 8];         \
        }                                                                     \
        _Pragma("unroll")                                                     \
        for (int i = 0; i < 2; ++i)                                           \
            _Pragma("unroll")                                                 \
            for (int j = 0; j < 4; ++j) {                                     \
                acc[i][j] = __builtin_amdgcn_mfma_f32_16x16x32_bf16(          \
                    ah[i], bh[j], acc[i][j], 0, 0, 0);                        \
                acc[i][j] = __builtin_amdgcn_mfma_f32_16x16x32_bf16(          \
                    ah[i], bl[j], acc[i][j], 0, 0, 0);                        \
                acc[i][j] = __builtin_amdgcn_mfma_f32_16x16x32_bf16(          \
                    al[i], bh[j], acc[i][j], 0, 0, 0);                        \
            }                                                                 \
    }

    LOADK(0)
    WRITEK(0)
    asm volatile("s_waitcnt lgkmcnt(0)" ::: "memory");
    __builtin_amdgcn_s_barrier();

    int cur = 0;
    for (int ks = 0; ks < 30; ++ks) {
        int knext = (ks < 29 ? ks + 1 : 29) * 32;
        LOADK(knext)          // issue next-tile loads (hide under compute)
        COMPUTEK(cur)
        WRITEK(cur ^ 1)       // ks=29 writes a dead buffer: harmless
        asm volatile("s_waitcnt lgkmcnt(0)" ::: "memory");
        __builtin_amdgcn_s_barrier();
        cur ^= 1;
    }

#pragma unroll
    for (int i = 0; i < 2; ++i)
#pragma unroll
        for (int j = 0; j < 4; ++j)
#pragma unroll
            for (int jr = 0; jr < 4; ++jr) {
                int row = bm + 32 * q + 16 * i + lk * 4 + jr;
                int col = bn + 16 * j + lr;
                C[(size_t)row * ldc + col] = acc[i][j][jr];
            }
#undef COMPUTEK
#undef WRITEK
#undef LOADK
}

// ---------------------------------------------------------------------------
// plain f32 GEMM (LoRA paths): C[M,N] = A[M,K] @ B[K,N]
// ---------------------------------------------------------------------------
__global__ __launch_bounds__(256) void gemm64_kernel(
    const float* __restrict__ A, int lda,
    const float* __restrict__ Bw, int ldb,
    float* __restrict__ Cc, int ldc, int N, int K)
{
    __shared__ float As[16][68];
    __shared__ float Bs[16][64];
    int bm = blockIdx.x * 64, bn = blockIdx.y * 64;
    int tid = threadIdx.x;
    int tx = tid & 15, ty = tid >> 4;
    int ar = tid >> 2, ak = (tid & 3) * 4;
    int bkr = tid >> 4, bnc = (tid & 15) * 4;
    bool bok = (bn + bnc) < N;
    const float* Aptr = A + (size_t)(bm + ar) * lda + ak;
    const float* Bptr = Bw + (size_t)bkr * ldb + bn + bnc;
    float acc[4][4];
#pragma unroll
    for (int i = 0; i < 4; ++i)
#pragma unroll
        for (int j = 0; j < 4; ++j) acc[i][j] = 0.f;

    for (int k0 = 0; k0 < K; k0 += 16) {
        float4 a4 = *(const float4*)(Aptr + k0);
        float4 b4 = make_float4(0.f, 0.f, 0.f, 0.f);
        if (bok) b4 = *(const float4*)(Bptr + (size_t)k0 * ldb);
        As[ak + 0][ar] = a4.x;
        As[ak + 1][ar] = a4.y;
        As[ak + 2][ar] = a4.z;
        As[ak + 3][ar] = a4.w;
        *(float4*)&Bs[bkr][bnc] = b4;
        __syncthreads();
#pragma unroll
        for (int kk = 0; kk < 16; ++kk) {
            float4 av = *(const float4*)&As[kk][ty * 4];
            float4 bv = *(const float4*)&Bs[kk][tx * 4];
            float aa[4] = {av.x, av.y, av.z, av.w};
            float bb[4] = {bv.x, bv.y, bv.z, bv.w};
#pragma unroll
            for (int i = 0; i < 4; ++i)
#pragma unroll
                for (int j = 0; j < 4; ++j) acc[i][j] += aa[i] * bb[j];
        }
        __syncthreads();
    }
    if (bok) {
#pragma unroll
        for (int i = 0; i < 4; ++i) {
            int row = bm + ty * 4 + i;
            float4 st = make_float4(acc[i][0], acc[i][1], acc[i][2], acc[i][3]);
            *(float4*)(Cc + (size_t)row * ldc + bn + tx * 4) = st;
        }
    }
}

// ---------------------------------------------------------------------------
// activations on hid: cols [0,64) tanh (w), [160,288) sigmoid (g)
// ---------------------------------------------------------------------------
__global__ __launch_bounds__(256) void hidact_kernel(float* hid)
{
    int idx = blockIdx.x * 256 + threadIdx.x;
    if (idx >= Mn * 288) return;
    int c = idx % 288;
    float v = hid[idx];
    if (c < 64) v = tanhf(v);
    else if (c >= 160) v = sigmf(v);
    hid[idx] = v;
}

// ---------------------------------------------------------------------------
// elementwise stage 3: w, a, v-residual, kk-norm, kh, ah, bh.
// ---------------------------------------------------------------------------
__global__ __launch_bounds__(256) void stage3e_kernel(
    const float* wrawp, const float* aprep, const float* vsigp,
    const float* kraw, const float* vfirst,
    const float* w0, const float* a0, const float* v0c,
    const float* kkc, const float* kac,
    float* w_out, float* v_io, float* ah_out, float* bh_out, float* kh_out)
{
    int p = blockIdx.x * 4 + (threadIdx.x >> 6);
    int l = threadIdx.x & 63;
    int m = p / Hn;
    int h = p - m * Hn;
    int c = h * 64 + l;
    size_t idx = (size_t)m * Cn + c;
    float k = kraw[idx];
    float wr = w0[c] + wrawp[idx];
    float a = sigmf(a0[c] + aprep[idx]);
    float vs = sigmf(v0c[c] + vsigp[idx]);
    float v0g = v_io[idx];
    float v = v0g + (vfirst[idx] - v0g) * vs;
    float kk = k * kkc[c];
    float ss = kk * kk;
#pragma unroll
    for (int o = 32; o; o >>= 1) ss += __shfl_xor(ss, o);
    float inv = 1.0f / fmaxf(sqrtf(ss), 1e-12f);
    kk *= inv;
    float w = sigmf(wr) * 0.60653065971263342f;  // sigmoid(wr)*exp(-0.5)
    float kh = k * (1.0f + (a - 1.0f) * kac[c]);
    w_out[idx] = w;
    v_io[idx] = v;
    ah_out[idx] = -kk;
    bh_out[idx] = kk * a;
    kh_out[idx] = kh;
}

// ---------------------------------------------------------------------------
// CHUNKED sequential WKV scan (unchanged from R6: 295us).
// ---------------------------------------------------------------------------
__global__ __launch_bounds__(256, 1) void scan_kernel(
    const float* __restrict__ rP, const float* __restrict__ wP,
    const float* __restrict__ kP, const float* __restrict__ aP,
    const float* __restrict__ bP, const float* __restrict__ vP,
    float* __restrict__ wkv)
{
    __shared__ float buf[2][6][16][64];  // 48 KB
    int tid = threadIdx.x;
    int q = tid >> 6, l = tid & 63;
    int bh = blockIdx.x;
    int bb = bh / Hn, h = bh - bb * Hn;
    size_t base = (size_t)bb * Tn * Cn + h * 64;
    int rl = l >> 2, cg = l & 3;
    int c0 = cg * 16;
    int arow = q * 16 + rl;

    size_t soff = base + (size_t)(tid >> 4) * Cn + (tid & 15) * 4;
    const float* pSr = rP + soff;
    const float* pSw = wP + soff;
    const float* pSk = kP + soff;
    const float* pSa = aP + soff;
    const float* pSb = bP + soff;
    const float* pSv = vP + soff;
    int wofs = (tid >> 4) * 64 + (tid & 15) * 4;

    float s[16];
#pragma unroll
    for (int z = 0; z < 16; ++z) s[z] = 0.f;

    float* po = wkv + base + arow;

    {
        float4 h0 = *(const float4*)(pSr);
        float4 h1 = *(const float4*)(pSw);
        float4 h2 = *(const float4*)(pSk);
        float4 h3 = *(const float4*)(pSa);
        float4 h4 = *(const float4*)(pSb);
        float4 h5 = *(const float4*)(pSv);
        float* bn = &buf[0][0][0][0];
        *(float4*)(bn + 0 * 1024 + wofs) = h0;
        *(float4*)(bn + 1 * 1024 + wofs) = h1;
        *(float4*)(bn + 2 * 1024 + wofs) = h2;
        *(float4*)(bn + 3 * 1024 + wofs) = h3;
        *(float4*)(bn + 4 * 1024 + wofs) = h4;
        *(float4*)(bn + 5 * 1024 + wofs) = h5;
        asm volatile("s_waitcnt lgkmcnt(0)" ::: "memory");
        __builtin_amdgcn_s_barrier();
    }

#define DECLSET(S)                                                            \
    float4 S##r[4], S##w[4], S##k[4], S##a[4], S##b[4];                       \
    float S##v;
#define DSLOAD(S, T)                                                          \
    {                                                                         \
        _Pragma("unroll")                                                     \
        for (int j = 0; j < 4; ++j) {                                         \
            S##r[j] = *(const float4*)(bc + 0 * 1024 + (T) * 64 + c0 + 4 * j);\
            S##w[j] = *(const float4*)(bc + 1 * 1024 + (T) * 64 + c0 + 4 * j);\
            S##k[j] = *(const float4*)(bc + 2 * 1024 + (T) * 64 + c0 + 4 * j);\
            S##a[j] = *(const float4*)(bc + 3 * 1024 + (T) * 64 + c0 + 4 * j);\
            S##b[j] = *(const float4*)(bc + 4 * 1024 + (T) * 64 + c0 + 4 * j);\
        }                                                                     \
        S##v = bc[5 * 1024 + (T) * 64 + arow];                                \
    }
#define COMPUTE(S)                                                            \
    {                                                                         \
        float sp0 = 0.f, sp1 = 0.f, sp2 = 0.f, sp3 = 0.f;                     \
        _Pragma("unroll")                                                     \
        for (int j = 0; j < 4; ++j) {                                         \
            sp0 += s[4 * j + 0] * S##a[j].x;                                  \
            sp1 += s[4 * j + 1] * S##a[j].y;                                  \
            sp2 += s[4 * j + 2] * S##a[j].z;                                  \
            sp3 += s[4 * j + 3] * S##a[j].w;                                  \
        }                                                                     \
        float sa = quadsum((sp0 + sp1) + (sp2 + sp3));                        \
        float vi = S##v;                                                      \
        float op0 = 0.f, op1 = 0.f, op2 = 0.f, op3 = 0.f;                     \
        _Pragma("unroll")                                                     \
        for (int j = 0; j < 4; ++j) {                                         \
            s[4 * j + 0] = s[4 * j + 0] * S##w[j].x + sa * S##b[j].x + vi * S##k[j].x; \
            op0 += s[4 * j + 0] * S##r[j].x;                                  \
            s[4 * j + 1] = s[4 * j + 1] * S##w[j].y + sa * S##b[j].y + vi * S##k[j].y; \
            op1 += s[4 * j + 1] * S##r[j].y;                                  \
            s[4 * j + 2] = s[4 * j + 2] * S##w[j].z + sa * S##b[j].z + vi * S##k[j].z; \
            op2 += s[4 * j + 2] * S##r[j].z;                                  \
            s[4 * j + 3] = s[4 * j + 3] * S##w[j].w + sa * S##b[j].w + vi * S##k[j].w; \
            op3 += s[4 * j + 3] * S##r[j].w;                                  \
        }                                                                     \
        float op = quadsum((op0 + op1) + (op2 + op3));                        \
        if (cg == 0) *po = op;                                                \
        po += Cn;                                                             \
    }

    DECLSET(A) DECLSET(B)

    int cur = 0;
    for (int c = 0; c < 64; ++c) {
        const float* bc = &buf[cur][0][0][0];
        size_t t2 = (size_t)((c < 63 ? c + 1 : 63) * 16) * Cn;
        float4 g0 = *(const float4*)(pSr + t2);
        float4 g1 = *(const float4*)(pSw + t2);
        float4 g2 = *(const float4*)(pSk + t2);
        float4 g3 = *(const float4*)(pSa + t2);
        float4 g4 = *(const float4*)(pSb + t2);
        float4 g5 = *(const float4*)(pSv + t2);

        DSLOAD(A, 0)
#pragma unroll
        for (int it = 0; it < 8; ++it) {
            DSLOAD(B, 2 * it + 1)
            COMPUTE(A)
            if (it < 7) { DSLOAD(A, 2 * it + 2) }
            COMPUTE(B)
        }

        float* bn = &buf[cur ^ 1][0][0][0];
        *(float4*)(bn + 0 * 1024 + wofs) = g0;
        *(float4*)(bn + 1 * 1024 + wofs) = g1;
        *(float4*)(bn + 2 * 1024 + wofs) = g2;
        *(float4*)(bn + 3 * 1024 + wofs) = g3;
        *(float4*)(bn + 4 * 1024 + wofs) = g4;
        *(float4*)(bn + 5 * 1024 + wofs) = g5;
        asm volatile("s_waitcnt lgkmcnt(0)" ::: "memory");
        __builtin_amdgcn_s_barrier();
        cur ^= 1;
    }
#undef COMPUTE
#undef DSLOAD
#undef DECLSET
}

// ---------------------------------------------------------------------------
// post-scan: per-head groupnorm + bonus + gate.  one wave per (m,h).
// ---------------------------------------------------------------------------
__global__ __launch_bounds__(256) void postnorm_kernel(
    const float* __restrict__ wkv, const float* __restrict__ rB,
    const float* __restrict__ kB, const float* __restrict__ vB,
    const float* __restrict__ gB, const float* __restrict__ r_k,
    const float* __restrict__ ln_g, const float* __restrict__ ln_b,
    float* __restrict__ xog)
{
    int grp = blockIdx.x * 4 + (threadIdx.x >> 6);
    int l = threadIdx.x & 63;
    int m = grp / Hn, h = grp - m * Hn;
    int c = h * 64 + l;
    size_t idx = (size_t)m * Cn + c;
    float out = wkv[idx];
    float rv = rB[idx], kv = kB[idx], vv = vB[idx];
    float m1 = out, m2 = out * out, bd = rv * kv * r_k[c];
#pragma unroll
    for (int o = 32; o; o >>= 1) {
        m1 += __shfl_xor(m1, o);
        m2 += __shfl_xor(m2, o);
        bd += __shfl_xor(bd, o);
    }
    float mean = m1 * (1.f / 64.f);
    float var = m2 * (1.f / 64.f) - mean * mean;
    float xn = (out - mean) * rsqrtf(var + 0.00064f) * ln_g[c] + ln_b[c];
    xog[idx] = (xn + bd * vv) * gB[idx];
}

// ---------------------------------------------------------------------------
extern "C" void kernel_launch(void* const* d_in, const int* in_sizes, int n_in,
                              void* d_out, int out_size, void* d_ws, size_t ws_size,
                              hipStream_t stream)
{
    const float* x       = (const float*)d_in[0];
    const float* v_first = (const float*)d_in[1];
    const float* x_r     = (const float*)d_in[2];
    const float* x_w     = (const float*)d_in[3];
    const float* x_k     = (const float*)d_in[4];
    const float* x_v     = (const float*)d_in[5];
    const float* x_a     = (const float*)d_in[6];
    const float* x_g     = (const float*)d_in[7];
    const float* w0      = (const float*)d_in[8];
    const float* w1      = (const float*)d_in[9];
    const float* w2      = (const float*)d_in[10];
    const float* a0      = (const float*)d_in[11];
    const float* a1      = (const float*)d_in[12];
    const float* a2      = (const float*)d_in[13];
    const float* v0c     = (const float*)d_in[14];
    const float* v1      = (const float*)d_in[15];
    const float* v2      = (const float*)d_in[16];
    const float* g1w     = (const float*)d_in[17];
    const float* g2w     = (const float*)d_in[18];
    const float* k_k     = (const float*)d_in[19];
    const float* k_a     = (const float*)d_in[20];
    const float* r_k     = (const float*)d_in[21];
    const float* Wr      = (const float*)d_in[22];
    const float* Wk      = (const float*)d_in[23];
    const float* Wv      = (const float*)d_in[24];
    const float* Wo      = (const float*)d_in[25];
    const float* ln_g    = (const float*)d_in[26];
    const float* ln_b    = (const float*)d_in[27];
    float* out = (float*)d_out;

    float* ws = (float*)d_ws;
    size_t MC = (size_t)Mn * Cn;
    float* B0 = ws + 0 * MC;  // xr -> wraw -> ah
    float* B1 = ws + 1 * MC;  // xw -> w    -> xog
    float* B2 = ws + 2 * MC;  // xk -> apre -> bh
    float* B3 = ws + 3 * MC;  // xv -> vsigp -> kh
    float* B4 = ws + 4 * MC;  // xa -> wkv -> xog-split (bf16)
    float* B5 = ws + 5 * MC;  // xg -> g
    float* B6 = ws + 6 * MC;  // r
    float* B7 = ws + 7 * MC;  // k (raw)
    float* B8 = ws + 8 * MC;  // v0 -> v
    float* hid = ws + 9 * MC; // [Mn,288] f32; also scratch for W-splits

    // scratch aliases (sequential-lifetime reuse, no extra workspace):
    ushort* Ahi = (ushort*)out;            // A-split lives in d_out until final GEMM
    ushort* Alo = Ahi + MC;
    ushort* Whi = (ushort*)hid;            // W-split lives in hid when hid is dead
    ushort* Wlo = Whi + (size_t)960 * 960;
    ushort* Xhi = (ushort*)B4;             // xog-split (B4 dead after postnorm)
    ushort* Xlo = Xhi + MC;

    mix6_kernel<<<3840, 256, 0, stream>>>(x, x_r, x_w, x_k, x_v, x_a, x_g,
                                          B0, B1, B2, B3, B4, B5);

    dim3 gW(30, 30);
    dim3 gM(32, 15);
    // stage 1: big projections via split-bf16 MFMA
    convWT_kernel<<<gW, 256, 0, stream>>>(Wr, Whi, Wlo);
    convA_kernel<<<3840, 256, 0, stream>>>(B0, Ahi, Alo);
    gemm_bf3_kernel<<<gM, 256, 0, stream>>>(Ahi, Alo, Whi, Wlo, B6, Cn);
    convWT_kernel<<<gW, 256, 0, stream>>>(Wk, Whi, Wlo);
    convA_kernel<<<3840, 256, 0, stream>>>(B2, Ahi, Alo);
    gemm_bf3_kernel<<<gM, 256, 0, stream>>>(Ahi, Alo, Whi, Wlo, B7, Cn);
    convWT_kernel<<<gW, 256, 0, stream>>>(Wv, Whi, Wlo);
    convA_kernel<<<3840, 256, 0, stream>>>(B3, Ahi, Alo);
    gemm_bf3_kernel<<<gM, 256, 0, stream>>>(Ahi, Alo, Whi, Wlo, B8, Cn);

    // stage 2: lora-down GEMMs into hid (f32; overwrites W-split scratch)
    dim3 g64(64, 1);
    gemm64_kernel<<<g64, 256, 0, stream>>>(B1, Cn, w1, 64, hid + 0, 288, 64, Cn);
    gemm64_kernel<<<g64, 256, 0, stream>>>(B4, Cn, a1, 64, hid + 64, 288, 64, Cn);
    gemm64_kernel<<<g64, 256, 0, stream>>>(B3, Cn, v1, 32, hid + 128, 288, 32, Cn);
    gemm64_kernel<<<dim3(64, 2), 256, 0, stream>>>(B5, Cn, g1w, 128, hid + 160, 288, 128, Cn);
    hidact_kernel<<<4608, 256, 0, stream>>>(hid);
    // stage 3: lora-up GEMMs
    gemm64_kernel<<<dim3(64, 15), 256, 0, stream>>>(hid + 0, 288, w2, Cn, B0, Cn, Cn, 64);
    gemm64_kernel<<<dim3(64, 15), 256, 0, stream>>>(hid + 64, 288, a2, Cn, B2, Cn, Cn, 64);
    gemm64_kernel<<<dim3(64, 15), 256, 0, stream>>>(hid + 128, 288, v2, Cn, B3, Cn, Cn, 32);
    gemm64_kernel<<<dim3(64, 15), 256, 0, stream>>>(hid + 160, 288, g2w, Cn, B5, Cn, Cn, 128);
    // stage 3e: elementwise + head-norm
    stage3e_kernel<<<15360, 256, 0, stream>>>(B0, B2, B3, B7, v_first,
                                              w0, a0, v0c, k_k, k_a,
                                              B1, B8, B0, B2, B3);
    // stage 4: chunked scan (raw wkv out)
    scan_kernel<<<60, 256, 0, stream>>>(B6, B1, B3, B0, B2, B8, B4);
    // stage 4b: groupnorm + bonus + gate
    postnorm_kernel<<<15360, 256, 0, stream>>>(B4, B6, B3, B8, B5,
                                               r_k, ln_g, ln_b, B1);
    // stage 5: output projection via split-bf16 MFMA (hid dead -> W scratch;
    // B4 dead -> xog-split; writes d_out which no longer holds A-split)
    convWT_kernel<<<gW, 256, 0, stream>>>(Wo, Whi, Wlo);
    convA_kernel<<<3840, 256, 0, stream>>>(B1, Xhi, Xlo);
    gemm_bf3_kernel<<<gM, 256, 0, stream>>>(Xhi, Xlo, Whi, Wlo, out, Cn);
}

// Round 8
// 810.393 us; speedup vs baseline: 1.6184x; 1.0023x over previous
//
#include <hip/hip_runtime.h>
#include <hip/hip_bf16.h>
#include <math.h>

#define Tn 1024
#define Cn 960
#define Hn 15
#define Nn 64
#define Mn 4096  // B*T

typedef short bf16x8 __attribute__((ext_vector_type(8)));
typedef float f32x4 __attribute__((ext_vector_type(4)));

__device__ __forceinline__ float sigmf(float x) { return 1.0f / (1.0f + __expf(-x)); }

// round-to-nearest-even f32 -> bf16 (as ushort)
__device__ __forceinline__ ushort f2bf(float x) {
    unsigned u = __float_as_uint(x);
    unsigned r = (u + 0x7FFFu + ((u >> 16) & 1u)) >> 16;
    return (ushort)r;
}
__device__ __forceinline__ float bf2f(ushort h) { return __uint_as_float(((unsigned)h) << 16); }

// full sum over the 16-lane DPP row via row_ror rotate-accumulate (all VALU).
__device__ __forceinline__ float rowsum16(float x) {
    x += __int_as_float(__builtin_amdgcn_update_dpp(0, __float_as_int(x), 0x121, 0xF, 0xF, true)); // ror:1
    x += __int_as_float(__builtin_amdgcn_update_dpp(0, __float_as_int(x), 0x122, 0xF, 0xF, true)); // ror:2
    x += __int_as_float(__builtin_amdgcn_update_dpp(0, __float_as_int(x), 0x124, 0xF, 0xF, true)); // ror:4
    x += __int_as_float(__builtin_amdgcn_update_dpp(0, __float_as_int(x), 0x128, 0xF, 0xF, true)); // ror:8
    return x;
}

// ---------------------------------------------------------------------------
// token-shift + 6 mixes: out_j = x + (shift(x) - x) * mix_j
// ---------------------------------------------------------------------------
__global__ __launch_bounds__(256) void mix6_kernel(
    const float* __restrict__ x,
    const float* __restrict__ mr, const float* __restrict__ mw, const float* __restrict__ mk,
    const float* __restrict__ mv, const float* __restrict__ ma, const float* __restrict__ mg,
    float* __restrict__ o_r, float* __restrict__ o_w, float* __restrict__ o_k,
    float* __restrict__ o_v, float* __restrict__ o_a, float* __restrict__ o_g)
{
    int idx = blockIdx.x * 256 + threadIdx.x;  // float4 index
    int e = idx * 4;
    if (e >= Mn * Cn) return;
    int m = e / Cn;
    int c = e - m * Cn;
    int t = m & (Tn - 1);
    float4 xv = *(const float4*)(x + e);
    float4 xp = make_float4(0.f, 0.f, 0.f, 0.f);
    if (t > 0) xp = *(const float4*)(x + e - Cn);
    float4 dx = make_float4(xp.x - xv.x, xp.y - xv.y, xp.z - xv.z, xp.w - xv.w);
#define APPLY(MIXP, OUTP)                                                     \
    {                                                                         \
        float4 mm = *(const float4*)(MIXP + c);                               \
        float4 o = make_float4(xv.x + dx.x * mm.x, xv.y + dx.y * mm.y,        \
                               xv.z + dx.z * mm.z, xv.w + dx.w * mm.w);       \
        *(float4*)(OUTP + e) = o;                                             \
    }
    APPLY(mr, o_r) APPLY(mw, o_w) APPLY(mk, o_k)
    APPLY(mv, o_v) APPLY(ma, o_a) APPLY(mg, o_g)
#undef APPLY
}

// ---------------------------------------------------------------------------
// split-convert activation: f32 [Mn][Cn] -> hi/lo bf16 (ushort) arrays
// ---------------------------------------------------------------------------
__global__ __launch_bounds__(256) void convA_kernel(
    const float* __restrict__ X, ushort* __restrict__ hi, ushort* __restrict__ lo)
{
    int idx = blockIdx.x * 256 + threadIdx.x;
    int e = idx * 4;
    if (e >= Mn * Cn) return;
    float4 x = *(const float4*)(X + e);
    ushort h0 = f2bf(x.x), h1 = f2bf(x.y), h2 = f2bf(x.z), h3 = f2bf(x.w);
    ushort l0 = f2bf(x.x - bf2f(h0)), l1 = f2bf(x.y - bf2f(h1));
    ushort l2 = f2bf(x.z - bf2f(h2)), l3 = f2bf(x.w - bf2f(h3));
    ushort4 hv = make_ushort4(h0, h1, h2, h3);
    ushort4 lv = make_ushort4(l0, l1, l2, l3);
    *(ushort4*)(hi + e) = hv;
    *(ushort4*)(lo + e) = lv;
}

// ---------------------------------------------------------------------------
// transpose + split-convert weight: W f32 [K=960][N=960] -> Thi/Tlo bf16 [N][K]
// ---------------------------------------------------------------------------
__global__ __launch_bounds__(256) void convWT_kernel(
    const float* __restrict__ W, ushort* __restrict__ Thi, ushort* __restrict__ Tlo)
{
    __shared__ float tile[32][33];
    int k0 = blockIdx.x * 32, n0 = blockIdx.y * 32;
    int tx = threadIdx.x & 31, ty = threadIdx.x >> 5;  // 32 x 8
#pragma unroll
    for (int i = 0; i < 4; ++i)
        tile[ty + 8 * i][tx] = W[(size_t)(k0 + ty + 8 * i) * 960 + n0 + tx];
    __syncthreads();
#pragma unroll
    for (int i = 0; i < 4; ++i) {
        float x = tile[tx][ty + 8 * i];
        ushort h = f2bf(x);
        ushort l = f2bf(x - bf2f(h));
        size_t o = (size_t)(n0 + ty + 8 * i) * 960 + k0 + tx;
        Thi[o] = h;
        Tlo[o] = l;
    }
}

// ---------------------------------------------------------------------------
// split-bf16 MFMA GEMM: C[M,N] = A[M,K] @ W[K,N], K=960, via
// Ahi@Whi + Ahi@Wlo + Alo@Whi  (lo*lo dropped, ~2^-18 relative).
// ---------------------------------------------------------------------------
__global__ __launch_bounds__(256) void gemm_bf3_kernel(
    const ushort* __restrict__ Ahi, const ushort* __restrict__ Alo,
    const ushort* __restrict__ Bhi, const ushort* __restrict__ Blo,
    float* __restrict__ C, int ldc)
{
    __shared__ __align__(16) ushort sA[2][2][128][40];
    __shared__ __align__(16) ushort sB[2][2][64][40];
    const int K = 960;
    int bm = blockIdx.x * 128, bn = blockIdx.y * 64;
    int t = threadIdx.x;
    int q = t >> 6, l = t & 63;
    int lr = l & 15, lk = l >> 4;

    int ar = t >> 1, aseg = t & 1;
    int br = t & 63, bhalf = (t >> 6) & 1, bseg = t >> 7;
    const ushort* gAh = Ahi + (size_t)(bm + ar) * K + aseg * 16;
    const ushort* gAl = Alo + (size_t)(bm + ar) * K + aseg * 16;
    const ushort* gB = (bhalf ? Blo : Bhi) + (size_t)(bn + br) * K + bseg * 16;

    f32x4 acc[2][4];
#pragma unroll
    for (int i = 0; i < 2; ++i)
#pragma unroll
        for (int j = 0; j < 4; ++j)
#pragma unroll
            for (int e = 0; e < 4; ++e) acc[i][j][e] = 0.f;

    float4 rh0, rh1, rl0, rl1, rb0, rb1;
#define LOADK(KOFF)                                                           \
    {                                                                         \
        rh0 = *(const float4*)(gAh + (KOFF));                                 \
        rh1 = *(const float4*)(gAh + (KOFF) + 8);                             \
        rl0 = *(const float4*)(gAl + (KOFF));                                 \
        rl1 = *(const float4*)(gAl + (KOFF) + 8);                             \
        rb0 = *(const float4*)(gB + (KOFF));                                  \
        rb1 = *(const float4*)(gB + (KOFF) + 8);                              \
    }
#define WRITEK(BUF)                                                           \
    {                                                                         \
        *(float4*)&sA[BUF][0][ar][aseg * 16] = rh0;                           \
        *(float4*)&sA[BUF][0][ar][aseg * 16 + 8] = rh1;                       \
        *(float4*)&sA[BUF][1][ar][aseg * 16] = rl0;                           \
        *(float4*)&sA[BUF][1][ar][aseg * 16 + 8] = rl1;                       \
        *(float4*)&sB[BUF][bhalf][br][bseg * 16] = rb0;                       \
        *(float4*)&sB[BUF][bhalf][br][bseg * 16 + 8] = rb1;                   \
    }
#define COMPUTEK(BUF)                                                         \
    {                                                                         \
        bf16x8 ah[2], al[2], bh[4], bl[4];                                    \
        _Pragma("unroll")                                                     \
        for (int i = 0; i < 2; ++i) {                                         \
            ah[i] = *(const bf16x8*)&sA[BUF][0][32 * q + 16 * i + lr][lk * 8];\
            al[i] = *(const bf16x8*)&sA[BUF][1][32 * q + 16 * i + lr][lk * 8];\
        }                                                                     \
        _Pragma("unroll")                                                     \
        for (int j = 0; j < 4; ++j) {                                         \
            bh[j] = *(const bf16x8*)&sB[BUF][0][16 * j + lr][lk * 8];         \
            bl[j] = *(const bf16x8*)&sB[BUF][1][16 * j + lr][lk * 8];         \
        }                                                                     \
        _Pragma("unroll")                                                     \
        for (int i = 0; i < 2; ++i)                                           \
            _Pragma("unroll")                                                 \
            for (int j = 0; j < 4; ++j) {                                     \
                acc[i][j] = __builtin_amdgcn_mfma_f32_16x16x32_bf16(          \
                    ah[i], bh[j], acc[i][j], 0, 0, 0);                        \
                acc[i][j] = __builtin_amdgcn_mfma_f32_16x16x32_bf16(          \
                    ah[i], bl[j], acc[i][j], 0, 0, 0);                        \
                acc[i][j] = __builtin_amdgcn_mfma_f32_16x16x32_bf16(          \
                    al[i], bh[j], acc[i][j], 0, 0, 0);                        \
            }                                                                 \
    }

    LOADK(0)
    WRITEK(0)
    asm volatile("s_waitcnt lgkmcnt(0)" ::: "memory");
    __builtin_amdgcn_s_barrier();

    int cur = 0;
    for (int ks = 0; ks < 30; ++ks) {
        int knext = (ks < 29 ? ks + 1 : 29) * 32;
        LOADK(knext)
        COMPUTEK(cur)
        WRITEK(cur ^ 1)
        asm volatile("s_waitcnt lgkmcnt(0)" ::: "memory");
        __builtin_amdgcn_s_barrier();
        cur ^= 1;
    }

#pragma unroll
    for (int i = 0; i < 2; ++i)
#pragma unroll
        for (int j = 0; j < 4; ++j)
#pragma unroll
            for (int jr = 0; jr < 4; ++jr) {
                int row = bm + 32 * q + 16 * i + lk * 4 + jr;
                int col = bn + 16 * j + lr;
                C[(size_t)row * ldc + col] = acc[i][j][jr];
            }
#undef COMPUTEK
#undef WRITEK
#undef LOADK
}

// ---------------------------------------------------------------------------
// plain f32 GEMM (LoRA paths): C[M,N] = A[M,K] @ B[K,N]
// ---------------------------------------------------------------------------
__global__ __launch_bounds__(256) void gemm64_kernel(
    const float* __restrict__ A, int lda,
    const float* __restrict__ Bw, int ldb,
    float* __restrict__ Cc, int ldc, int N, int K)
{
    __shared__ float As[16][68];
    __shared__ float Bs[16][64];
    int bm = blockIdx.x * 64, bn = blockIdx.y * 64;
    int tid = threadIdx.x;
    int tx = tid & 15, ty = tid >> 4;
    int ar = tid >> 2, ak = (tid & 3) * 4;
    int bkr = tid >> 4, bnc = (tid & 15) * 4;
    bool bok = (bn + bnc) < N;
    const float* Aptr = A + (size_t)(bm + ar) * lda + ak;
    const float* Bptr = Bw + (size_t)bkr * ldb + bn + bnc;
    float acc[4][4];
#pragma unroll
    for (int i = 0; i < 4; ++i)
#pragma unroll
        for (int j = 0; j < 4; ++j) acc[i][j] = 0.f;

    for (int k0 = 0; k0 < K; k0 += 16) {
        float4 a4 = *(const float4*)(Aptr + k0);
        float4 b4 = make_float4(0.f, 0.f, 0.f, 0.f);
        if (bok) b4 = *(const float4*)(Bptr + (size_t)k0 * ldb);
        As[ak + 0][ar] = a4.x;
        As[ak + 1][ar] = a4.y;
        As[ak + 2][ar] = a4.z;
        As[ak + 3][ar] = a4.w;
        *(float4*)&Bs[bkr][bnc] = b4;
        __syncthreads();
#pragma unroll
        for (int kk = 0; kk < 16; ++kk) {
            float4 av = *(const float4*)&As[kk][ty * 4];
            float4 bv = *(const float4*)&Bs[kk][tx * 4];
            float aa[4] = {av.x, av.y, av.z, av.w};
            float bb[4] = {bv.x, bv.y, bv.z, bv.w};
#pragma unroll
            for (int i = 0; i < 4; ++i)
#pragma unroll
                for (int j = 0; j < 4; ++j) acc[i][j] += aa[i] * bb[j];
        }
        __syncthreads();
    }
    if (bok) {
#pragma unroll
        for (int i = 0; i < 4; ++i) {
            int row = bm + ty * 4 + i;
            float4 st = make_float4(acc[i][0], acc[i][1], acc[i][2], acc[i][3]);
            *(float4*)(Cc + (size_t)row * ldc + bn + tx * 4) = st;
        }
    }
}

// ---------------------------------------------------------------------------
// activations on hid: cols [0,64) tanh (w), [160,288) sigmoid (g)
// ---------------------------------------------------------------------------
__global__ __launch_bounds__(256) void hidact_kernel(float* hid)
{
    int idx = blockIdx.x * 256 + threadIdx.x;
    if (idx >= Mn * 288) return;
    int c = idx % 288;
    float v = hid[idx];
    if (c < 64) v = tanhf(v);
    else if (c >= 160) v = sigmf(v);
    hid[idx] = v;
}

// ---------------------------------------------------------------------------
// elementwise stage 3: w, a, v-residual, kk-norm, kh, ah, bh.
// ---------------------------------------------------------------------------
__global__ __launch_bounds__(256) void stage3e_kernel(
    const float* wrawp, const float* aprep, const float* vsigp,
    const float* kraw, const float* vfirst,
    const float* w0, const float* a0, const float* v0c,
    const float* kkc, const float* kac,
    float* w_out, float* v_io, float* ah_out, float* bh_out, float* kh_out)
{
    int p = blockIdx.x * 4 + (threadIdx.x >> 6);
    int l = threadIdx.x & 63;
    int m = p / Hn;
    int h = p - m * Hn;
    int c = h * 64 + l;
    size_t idx = (size_t)m * Cn + c;
    float k = kraw[idx];
    float wr = w0[c] + wrawp[idx];
    float a = sigmf(a0[c] + aprep[idx]);
    float vs = sigmf(v0c[c] + vsigp[idx]);
    float v0g = v_io[idx];
    float v = v0g + (vfirst[idx] - v0g) * vs;
    float kk = k * kkc[c];
    float ss = kk * kk;
#pragma unroll
    for (int o = 32; o; o >>= 1) ss += __shfl_xor(ss, o);
    float inv = 1.0f / fmaxf(sqrtf(ss), 1e-12f);
    kk *= inv;
    float w = sigmf(wr) * 0.60653065971263342f;  // sigmoid(wr)*exp(-0.5)
    float kh = k * (1.0f + (a - 1.0f) * kac[c]);
    w_out[idx] = w;
    v_io[idx] = v;
    ah_out[idx] = -kk;
    bh_out[idx] = kk * a;
    kh_out[idx] = kh;
}

// ---------------------------------------------------------------------------
// CHUNKED scan, 4x4 lane tile + fused groupnorm/bonus/gate.
// One block (4 waves) per (b,h) chain. Wave q owns rows [16q,16q+16); lane
// (rg=l>>4, cg=l&15) owns rows [16q+4rg,+4) x cols [4cg,+4) -> s[4][4].
// Per step: 6 ds_read_b128/lane (4x less LDS BW than 16-col layout);
// 16-lane reductions via DPP row_ror (VALU). Chunked staging (16 steps,
// double-buffered, issue-early/write-late). Norm fused at chunk end.
// ---------------------------------------------------------------------------
__global__ __launch_bounds__(256, 1) void scan_kernel(
    const float* __restrict__ rP, const float* __restrict__ wP,
    const float* __restrict__ kP, const float* __restrict__ aP,
    const float* __restrict__ bP, const float* __restrict__ vP,
    const float* __restrict__ gP, const float* __restrict__ r_k,
    const float* __restrict__ ln_g, const float* __restrict__ ln_b,
    float* __restrict__ xog)
{
    __shared__ float buf[2][7][16][64];  // 56 KB: [half][r,w,k,a,b,v,g][step][ch]
    __shared__ float outL[16][64];       // 4 KB per-chunk raw wkv
    int tid = threadIdx.x;
    int q = tid >> 6, l = tid & 63;
    int bh = blockIdx.x;
    int bb = bh / Hn, h = bh - bb * Hn;
    size_t base = (size_t)bb * Tn * Cn + h * 64;
    int rg = l >> 4, cg = l & 15;
    int row0 = 16 * q + 4 * rg;   // first of this lane's 4 rows
    int c0 = 4 * cg;              // first of this lane's 4 cols

    // staging: thread stages step (tid>>4), 16B seg (tid&15), all 7 vectors
    size_t soff = base + (size_t)(tid >> 4) * Cn + (tid & 15) * 4;
    const float* pS0 = rP + soff;
    const float* pS1 = wP + soff;
    const float* pS2 = kP + soff;
    const float* pS3 = aP + soff;
    const float* pS4 = bP + soff;
    const float* pS5 = vP + soff;
    const float* pS6 = gP + soff;
    int wofs = (tid >> 4) * 64 + (tid & 15) * 4;

    // norm-pass constants (thread = (tt = tid>>4, cc = tid&15))
    int tt = tid >> 4, cc = tid & 15;
    float4 rk4 = *(const float4*)(r_k + h * 64 + 4 * cc);
    float4 lg4 = *(const float4*)(ln_g + h * 64 + 4 * cc);
    float4 lb4 = *(const float4*)(ln_b + h * 64 + 4 * cc);

    float s[4][4];
#pragma unroll
    for (int r = 0; r < 4; ++r)
#pragma unroll
        for (int c = 0; c < 4; ++c) s[r][c] = 0.f;

    // ---- stage chunk 0 into buf[0]
    {
        float4 g0 = *(const float4*)pS0;
        float4 g1 = *(const float4*)pS1;
        float4 g2 = *(const float4*)pS2;
        float4 g3 = *(const float4*)pS3;
        float4 g4 = *(const float4*)pS4;
        float4 g5 = *(const float4*)pS5;
        float4 g6 = *(const float4*)pS6;
        float* bn = &buf[0][0][0][0];
        *(float4*)(bn + 0 * 1024 + wofs) = g0;
        *(float4*)(bn + 1 * 1024 + wofs) = g1;
        *(float4*)(bn + 2 * 1024 + wofs) = g2;
        *(float4*)(bn + 3 * 1024 + wofs) = g3;
        *(float4*)(bn + 4 * 1024 + wofs) = g4;
        *(float4*)(bn + 5 * 1024 + wofs) = g5;
        *(float4*)(bn + 6 * 1024 + wofs) = g6;
        asm volatile("s_waitcnt lgkmcnt(0)" ::: "memory");
        __builtin_amdgcn_s_barrier();
    }

    int cur = 0;
    for (int c = 0; c < 64; ++c) {
        const float* bc = &buf[cur][0][0][0];
        // issue staging loads for chunk c+1 (latency hidden under 16 steps)
        size_t t2 = (size_t)((c < 63 ? c + 1 : 63) * 16) * Cn;
        float4 g0 = *(const float4*)(pS0 + t2);
        float4 g1 = *(const float4*)(pS1 + t2);
        float4 g2 = *(const float4*)(pS2 + t2);
        float4 g3 = *(const float4*)(pS3 + t2);
        float4 g4 = *(const float4*)(pS4 + t2);
        float4 g5 = *(const float4*)(pS5 + t2);
        float4 g6 = *(const float4*)(pS6 + t2);

#pragma unroll
        for (int t = 0; t < 16; ++t) {
            float4 av = *(const float4*)(bc + 3 * 1024 + t * 64 + c0);
            float sp0 = s[0][0] * av.x + s[0][1] * av.y + s[0][2] * av.z + s[0][3] * av.w;
            float sp1 = s[1][0] * av.x + s[1][1] * av.y + s[1][2] * av.z + s[1][3] * av.w;
            float sp2 = s[2][0] * av.x + s[2][1] * av.y + s[2][2] * av.z + s[2][3] * av.w;
            float sp3 = s[3][0] * av.x + s[3][1] * av.y + s[3][2] * av.z + s[3][3] * av.w;
            sp0 = rowsum16(sp0);
            sp1 = rowsum16(sp1);
            sp2 = rowsum16(sp2);
            sp3 = rowsum16(sp3);
            float4 wv = *(const float4*)(bc + 1 * 1024 + t * 64 + c0);
            float4 kv = *(const float4*)(bc + 2 * 1024 + t * 64 + c0);
            float4 bv = *(const float4*)(bc + 4 * 1024 + t * 64 + c0);
            float4 rv = *(const float4*)(bc + 0 * 1024 + t * 64 + c0);
            float4 vv = *(const float4*)(bc + 5 * 1024 + t * 64 + row0);
            float sa[4] = {sp0, sp1, sp2, sp3};
            float vr[4] = {vv.x, vv.y, vv.z, vv.w};
            float op[4];
#pragma unroll
            for (int r = 0; r < 4; ++r) {
                s[r][0] = s[r][0] * wv.x + sa[r] * bv.x + vr[r] * kv.x;
                float o = s[r][0] * rv.x;
                s[r][1] = s[r][1] * wv.y + sa[r] * bv.y + vr[r] * kv.y;
                o += s[r][1] * rv.y;
                s[r][2] = s[r][2] * wv.z + sa[r] * bv.z + vr[r] * kv.z;
                o += s[r][2] * rv.z;
                s[r][3] = s[r][3] * wv.w + sa[r] * bv.w + vr[r] * kv.w;
                o += s[r][3] * rv.w;
                op[r] = rowsum16(o);
            }
            if (cg == 0)
                *(float4*)&outL[t][row0] = make_float4(op[0], op[1], op[2], op[3]);
        }

        // park staged regs into the other LDS half
        {
            float* bn = &buf[cur ^ 1][0][0][0];
            *(float4*)(bn + 0 * 1024 + wofs) = g0;
            *(float4*)(bn + 1 * 1024 + wofs) = g1;
            *(float4*)(bn + 2 * 1024 + wofs) = g2;
            *(float4*)(bn + 3 * 1024 + wofs) = g3;
            *(float4*)(bn + 4 * 1024 + wofs) = g4;
            *(float4*)(bn + 5 * 1024 + wofs) = g5;
            *(float4*)(bn + 6 * 1024 + wofs) = g6;
        }
        asm volatile("s_waitcnt lgkmcnt(0)" ::: "memory");
        __builtin_amdgcn_s_barrier();

        // ---- fused groupnorm + bonus + gate for this chunk
        {
            float4 o4 = *(const float4*)&outL[tt][4 * cc];
            float4 r4 = *(const float4*)(bc + 0 * 1024 + tt * 64 + 4 * cc);
            float4 k4 = *(const float4*)(bc + 2 * 1024 + tt * 64 + 4 * cc);
            float4 v4 = *(const float4*)(bc + 5 * 1024 + tt * 64 + 4 * cc);
            float4 gg4 = *(const float4*)(bc + 6 * 1024 + tt * 64 + 4 * cc);
            float m1 = o4.x + o4.y + o4.z + o4.w;
            float m2 = o4.x * o4.x + o4.y * o4.y + o4.z * o4.z + o4.w * o4.w;
            float bd = r4.x * k4.x * rk4.x + r4.y * k4.y * rk4.y +
                       r4.z * k4.z * rk4.z + r4.w * k4.w * rk4.w;
            m1 = rowsum16(m1);
            m2 = rowsum16(m2);
            bd = rowsum16(bd);
            float mean = m1 * (1.f / 64.f);
            float var = m2 * (1.f / 64.f) - mean * mean;
            float is = rsqrtf(var + 0.00064f);
            float4 xo;
            xo.x = ((o4.x - mean) * is * lg4.x + lb4.x + bd * v4.x) * gg4.x;
            xo.y = ((o4.y - mean) * is * lg4.y + lb4.y + bd * v4.y) * gg4.y;
            xo.z = ((o4.z - mean) * is * lg4.z + lb4.z + bd * v4.z) * gg4.z;
            xo.w = ((o4.w - mean) * is * lg4.w + lb4.w + bd * v4.w) * gg4.w;
            size_t gt = (size_t)c * 16 + tt;
            *(float4*)(xog + base + gt * Cn + 4 * cc) = xo;
        }
        __builtin_amdgcn_s_barrier();  // norm done before outL/buf[cur] reuse
        cur ^= 1;
    }
}

// ---------------------------------------------------------------------------
extern "C" void kernel_launch(void* const* d_in, const int* in_sizes, int n_in,
                              void* d_out, int out_size, void* d_ws, size_t ws_size,
                              hipStream_t stream)
{
    const float* x       = (const float*)d_in[0];
    const float* v_first = (const float*)d_in[1];
    const float* x_r     = (const float*)d_in[2];
    const float* x_w     = (const float*)d_in[3];
    const float* x_k     = (const float*)d_in[4];
    const float* x_v     = (const float*)d_in[5];
    const float* x_a     = (const float*)d_in[6];
    const float* x_g     = (const float*)d_in[7];
    const float* w0      = (const float*)d_in[8];
    const float* w1      = (const float*)d_in[9];
    const float* w2      = (const float*)d_in[10];
    const float* a0      = (const float*)d_in[11];
    const float* a1      = (const float*)d_in[12];
    const float* a2      = (const float*)d_in[13];
    const float* v0c     = (const float*)d_in[14];
    const float* v1      = (const float*)d_in[15];
    const float* v2      = (const float*)d_in[16];
    const float* g1w     = (const float*)d_in[17];
    const float* g2w     = (const float*)d_in[18];
    const float* k_k     = (const float*)d_in[19];
    const float* k_a     = (const float*)d_in[20];
    const float* r_k     = (const float*)d_in[21];
    const float* Wr      = (const float*)d_in[22];
    const float* Wk      = (const float*)d_in[23];
    const float* Wv      = (const float*)d_in[24];
    const float* Wo      = (const float*)d_in[25];
    const float* ln_g    = (const float*)d_in[26];
    const float* ln_b    = (const float*)d_in[27];
    float* out = (float*)d_out;

    float* ws = (float*)d_ws;
    size_t MC = (size_t)Mn * Cn;
    float* B0 = ws + 0 * MC;  // xr -> wraw -> ah
    float* B1 = ws + 1 * MC;  // xw -> w    -> xog
    float* B2 = ws + 2 * MC;  // xk -> apre -> bh
    float* B3 = ws + 3 * MC;  // xv -> vsigp -> kh
    float* B4 = ws + 4 * MC;  // xa -> xog-split scratch (bf16)
    float* B5 = ws + 5 * MC;  // xg -> g
    float* B6 = ws + 6 * MC;  // r
    float* B7 = ws + 7 * MC;  // k (raw)
    float* B8 = ws + 8 * MC;  // v0 -> v
    float* hid = ws + 9 * MC; // [Mn,288] f32; also scratch for W-splits

    ushort* Ahi = (ushort*)out;            // A-split lives in d_out until final GEMM
    ushort* Alo = Ahi + MC;
    ushort* Whi = (ushort*)hid;            // W-split lives in hid when hid is dead
    ushort* Wlo = Whi + (size_t)960 * 960;
    ushort* Xhi = (ushort*)B4;             // xog-split (B4 dead after scan)
    ushort* Xlo = Xhi + MC;

    mix6_kernel<<<3840, 256, 0, stream>>>(x, x_r, x_w, x_k, x_v, x_a, x_g,
                                          B0, B1, B2, B3, B4, B5);

    dim3 gW(30, 30);
    dim3 gM(32, 15);
    // stage 1: big projections via split-bf16 MFMA
    convWT_kernel<<<gW, 256, 0, stream>>>(Wr, Whi, Wlo);
    convA_kernel<<<3840, 256, 0, stream>>>(B0, Ahi, Alo);
    gemm_bf3_kernel<<<gM, 256, 0, stream>>>(Ahi, Alo, Whi, Wlo, B6, Cn);
    convWT_kernel<<<gW, 256, 0, stream>>>(Wk, Whi, Wlo);
    convA_kernel<<<3840, 256, 0, stream>>>(B2, Ahi, Alo);
    gemm_bf3_kernel<<<gM, 256, 0, stream>>>(Ahi, Alo, Whi, Wlo, B7, Cn);
    convWT_kernel<<<gW, 256, 0, stream>>>(Wv, Whi, Wlo);
    convA_kernel<<<3840, 256, 0, stream>>>(B3, Ahi, Alo);
    gemm_bf3_kernel<<<gM, 256, 0, stream>>>(Ahi, Alo, Whi, Wlo, B8, Cn);

    // stage 2: lora-down GEMMs into hid (f32; overwrites W-split scratch)
    dim3 g64(64, 1);
    gemm64_kernel<<<g64, 256, 0, stream>>>(B1, Cn, w1, 64, hid + 0, 288, 64, Cn);
    gemm64_kernel<<<g64, 256, 0, stream>>>(B4, Cn, a1, 64, hid + 64, 288, 64, Cn);
    gemm64_kernel<<<g64, 256, 0, stream>>>(B3, Cn, v1, 32, hid + 128, 288, 32, Cn);
    gemm64_kernel<<<dim3(64, 2), 256, 0, stream>>>(B5, Cn, g1w, 128, hid + 160, 288, 128, Cn);
    hidact_kernel<<<4608, 256, 0, stream>>>(hid);
    // stage 3: lora-up GEMMs
    gemm64_kernel<<<dim3(64, 15), 256, 0, stream>>>(hid + 0, 288, w2, Cn, B0, Cn, Cn, 64);
    gemm64_kernel<<<dim3(64, 15), 256, 0, stream>>>(hid + 64, 288, a2, Cn, B2, Cn, Cn, 64);
    gemm64_kernel<<<dim3(64, 15), 256, 0, stream>>>(hid + 128, 288, v2, Cn, B3, Cn, Cn, 32);
    gemm64_kernel<<<dim3(64, 15), 256, 0, stream>>>(hid + 160, 288, g2w, Cn, B5, Cn, Cn, 128);
    // stage 3e: elementwise + head-norm
    stage3e_kernel<<<15360, 256, 0, stream>>>(B0, B2, B3, B7, v_first,
                                              w0, a0, v0c, k_k, k_a,
                                              B1, B8, B0, B2, B3);
    // stage 4: chunked scan + fused groupnorm/bonus/gate -> xog in B1
    // (writes to B1[t] happen only after all reads of B1[t] as w; staging
    //  for chunk c+1 is issued before norm writes chunk c — disjoint rows)
    scan_kernel<<<60, 256, 0, stream>>>(B6, B1, B3, B0, B2, B8, B5,
                                        r_k, ln_g, ln_b, B1);
    // stage 5: output projection via split-bf16 MFMA
    convWT_kernel<<<gW, 256, 0, stream>>>(Wo, Whi, Wlo);
    convA_kernel<<<3840, 256, 0, stream>>>(B1, Xhi, Xlo);
    gemm_bf3_kernel<<<gM, 256, 0, stream>>>(Xhi, Xlo, Whi, Wlo, out, Cn);
}